// Round 1
// baseline (3378.417 us; speedup 1.0000x reference)
//
#include <hip/hip_runtime.h>
#include <math.h>

#define H  64
#define F  32
#define NB 4     // batch elements per block
#define NT 256   // threads per block == 4*H gate rows

__device__ __forceinline__ float sigmoidf_(float v) {
    return 1.0f / (1.0f + expf(-v));
}

__global__ __launch_bounds__(NT, 1)
void lstm_fused(const float* __restrict__ x,     // [B,T,F]
                const float* __restrict__ Wih0,  // [4H,F]
                const float* __restrict__ Whh0,  // [4H,H]
                const float* __restrict__ bih0,
                const float* __restrict__ bhh0,
                const float* __restrict__ Wih1,  // [4H,H]
                const float* __restrict__ Whh1,  // [4H,H]
                const float* __restrict__ bih1,
                const float* __restrict__ bhh1,
                const float* __restrict__ fcw,   // [1,H]
                const float* __restrict__ fcb,   // [1]
                float* __restrict__ out,         // [B]
                int T, int B)
{
    const int tid = threadIdx.x;
    const int r   = tid;                 // gate row this thread owns (0..255)
    const int b0  = blockIdx.x * NB;     // first batch element of this block

    // ---- load this row's weights into registers (loop-invariant) ----
    float wih0[F], whh0[H], wih1[H], whh1[H];
    #pragma unroll
    for (int k = 0; k < F; ++k) wih0[k] = Wih0[r * F + k];
    #pragma unroll
    for (int k = 0; k < H; ++k) whh0[k] = Whh0[r * H + k];
    #pragma unroll
    for (int k = 0; k < H; ++k) wih1[k] = Wih1[r * H + k];
    #pragma unroll
    for (int k = 0; k < H; ++k) whh1[k] = Whh1[r * H + k];
    const float bias0 = bih0[r] + bhh0[r];
    const float bias1 = bih1[r] + bhh1[r];

    // ---- state-update mapping: this thread owns (batch bu, hidden ju) ----
    const int bu = tid >> 6;   // 0..3  (== wave id)
    const int ju = tid & 63;   // 0..63 (== lane id)
    float c0 = 0.0f, c1 = 0.0f;
    const float fcw_j = fcw[ju];
    const float fcb0  = fcb[0];

    __shared__ float x_lds[F][NB];        // x[t] transposed: [k][b]
    __shared__ float h0_lds[H][NB];       // layer0 hidden  : [k][b]
    __shared__ float h1_lds[H][NB];       // layer1 hidden  : [k][b]
    __shared__ float g_lds[4 * H][NB + 1];// gates, stride 5 (bank-friendly)

    // ---- init h=0 and stage x(t=0) ----
    if (tid < H * NB) {
        (&h0_lds[0][0])[tid] = 0.0f;
        (&h1_lds[0][0])[tid] = 0.0f;
    }
    if (tid < F * NB) {                   // tid < 128
        const int bb = tid >> 5, k = tid & 31;
        x_lds[k][bb] = x[((size_t)(b0 + bb) * T + 0) * F + k];
    }
    __syncthreads();

    #pragma unroll 1
    for (int t = 0; t < T; ++t) {
        // prefetch x(t+1) into registers (consumed at end of step)
        float xpre = 0.0f;
        const int bb = tid >> 5, kk = tid & 31;
        if (tid < F * NB && (t + 1) < T) {
            xpre = x[((size_t)(b0 + bb) * T + (t + 1)) * F + kk];
        }

        // ================= gate phase, layer 0 =================
        float a0 = bias0, a1 = bias0, a2 = bias0, a3 = bias0;
        #pragma unroll
        for (int k = 0; k < F; ++k) {
            const float4 v = *reinterpret_cast<const float4*>(&x_lds[k][0]);
            a0 = fmaf(wih0[k], v.x, a0);
            a1 = fmaf(wih0[k], v.y, a1);
            a2 = fmaf(wih0[k], v.z, a2);
            a3 = fmaf(wih0[k], v.w, a3);
        }
        #pragma unroll
        for (int k = 0; k < H; ++k) {
            const float4 v = *reinterpret_cast<const float4*>(&h0_lds[k][0]);
            a0 = fmaf(whh0[k], v.x, a0);
            a1 = fmaf(whh0[k], v.y, a1);
            a2 = fmaf(whh0[k], v.z, a2);
            a3 = fmaf(whh0[k], v.w, a3);
        }
        g_lds[r][0] = a0; g_lds[r][1] = a1; g_lds[r][2] = a2; g_lds[r][3] = a3;
        __syncthreads();   // B: gates0 ready; old-h0 reads done

        // ================= update phase, layer 0 =================
        {
            float gi = g_lds[      ju][bu];
            float gf = g_lds[ 64 + ju][bu];
            float gg = g_lds[128 + ju][bu];
            float go = g_lds[192 + ju][bu];
            gi = sigmoidf_(gi);
            gf = sigmoidf_(gf);
            gg = tanhf(gg);
            go = sigmoidf_(go);
            c0 = gf * c0 + gi * gg;
            const float h = go * tanhf(c0);
            h0_lds[ju][bu] = h;
        }
        __syncthreads();   // C: new h0 ready; gates0 reads done

        // ================= gate phase, layer 1 =================
        a0 = bias1; a1 = bias1; a2 = bias1; a3 = bias1;
        #pragma unroll
        for (int k = 0; k < H; ++k) {
            const float4 v = *reinterpret_cast<const float4*>(&h0_lds[k][0]);
            a0 = fmaf(wih1[k], v.x, a0);
            a1 = fmaf(wih1[k], v.y, a1);
            a2 = fmaf(wih1[k], v.z, a2);
            a3 = fmaf(wih1[k], v.w, a3);
        }
        #pragma unroll
        for (int k = 0; k < H; ++k) {
            const float4 v = *reinterpret_cast<const float4*>(&h1_lds[k][0]);
            a0 = fmaf(whh1[k], v.x, a0);
            a1 = fmaf(whh1[k], v.y, a1);
            a2 = fmaf(whh1[k], v.z, a2);
            a3 = fmaf(whh1[k], v.w, a3);
        }
        g_lds[r][0] = a0; g_lds[r][1] = a1; g_lds[r][2] = a2; g_lds[r][3] = a3;
        __syncthreads();   // D: gates1 ready; old-h1/new-h0 reads done

        // ================= update phase, layer 1 (+x stage, +head) ==========
        {
            float gi = g_lds[      ju][bu];
            float gf = g_lds[ 64 + ju][bu];
            float gg = g_lds[128 + ju][bu];
            float go = g_lds[192 + ju][bu];
            gi = sigmoidf_(gi);
            gf = sigmoidf_(gf);
            gg = tanhf(gg);
            go = sigmoidf_(go);
            c1 = gf * c1 + gi * gg;
            const float h = go * tanhf(c1);
            h1_lds[ju][bu] = h;

            if (t == T - 1) {
                // fc head: out[b] = sum_j h1[b][j]*fcw[j] + fcb
                float v = h * fcw_j;
                #pragma unroll
                for (int off = 32; off > 0; off >>= 1)
                    v += __shfl_down(v, off);
                if (ju == 0) out[b0 + bu] = v + fcb0;
            }
        }
        if (tid < F * NB) {
            x_lds[kk][bb] = xpre;   // stage x(t+1); x(t) reads finished at B
        }
        __syncthreads();   // A: h1/x(t+1) ready for next step
    }
}

extern "C" void kernel_launch(void* const* d_in, const int* in_sizes, int n_in,
                              void* d_out, int out_size, void* d_ws, size_t ws_size,
                              hipStream_t stream) {
    const float* x    = (const float*)d_in[0];
    const float* Wih0 = (const float*)d_in[1];
    const float* Whh0 = (const float*)d_in[2];
    const float* bih0 = (const float*)d_in[3];
    const float* bhh0 = (const float*)d_in[4];
    const float* Wih1 = (const float*)d_in[5];
    const float* Whh1 = (const float*)d_in[6];
    const float* bih1 = (const float*)d_in[7];
    const float* bhh1 = (const float*)d_in[8];
    const float* fcw  = (const float*)d_in[9];
    const float* fcb  = (const float*)d_in[10];
    float* out = (float*)d_out;

    const int B = out_size;                 // 1024
    const int T = in_sizes[0] / (B * F);    // 512

    dim3 grid(B / NB), block(NT);
    hipLaunchKernelGGL(lstm_fused, grid, block, 0, stream,
                       x, Wih0, Whh0, bih0, bhh0,
                       Wih1, Whh1, bih1, bhh1, fcw, fcb,
                       out, T, B);
}

// Round 2
// 811.312 us; speedup vs baseline: 4.1641x; 4.1641x over previous
//
#include <hip/hip_runtime.h>
#include <math.h>

#define H  64
#define F  32
#define NB 16     // batch columns per block (= MFMA N)
#define NT 256    // 4 waves
#define HS 72     // LDS row stride (shorts) for h arrays (16B multiple)
#define XS 40     // LDS row stride (shorts) for x arrays (16B multiple)

typedef __attribute__((ext_vector_type(8))) short   s8v;   // 8 bf16 payload
typedef __attribute__((ext_vector_type(8))) __bf16  bf8v;  // MFMA operand type
typedef __attribute__((ext_vector_type(4))) float   f4v;   // MFMA accumulator

__device__ __forceinline__ unsigned short f2bf(float x) {
    unsigned u = __builtin_bit_cast(unsigned, x);
    u += 0x7FFFu + ((u >> 16) & 1u);          // RNE
    return (unsigned short)(u >> 16);
}
__device__ __forceinline__ float bf2f(unsigned short h) {
    unsigned u = ((unsigned)h) << 16;
    return __builtin_bit_cast(float, u);
}
__device__ __forceinline__ f4v mfma_(s8v a, s8v b, f4v c) {
    return __builtin_amdgcn_mfma_f32_16x16x32_bf16(
        __builtin_bit_cast(bf8v, a), __builtin_bit_cast(bf8v, b), c, 0, 0, 0);
}
__device__ __forceinline__ float sig_(float x) {
    return __builtin_amdgcn_rcpf(1.0f + __expf(-x));
}
__device__ __forceinline__ float tanh_(float x) {
    return 1.0f - 2.0f * __builtin_amdgcn_rcpf(1.0f + __expf(2.0f * x));
}

// Load an 8-wide A-fragment slice of a weight row, split hi/lo bf16.
__device__ __forceinline__ void load_frag(const float* __restrict__ Wrow, int koff,
                                          s8v& hi, s8v& lo) {
    #pragma unroll
    for (int i = 0; i < 8; ++i) {
        float v = Wrow[koff + i];
        unsigned short h = f2bf(v);
        hi[i] = (short)h;
        lo[i] = (short)f2bf(v - bf2f(h));
    }
}

__global__ __launch_bounds__(NT, 1)
void lstm_mfma(const float* __restrict__ x,     // [B,T,F]
               const float* __restrict__ Wih0,  // [4H,F]
               const float* __restrict__ Whh0,  // [4H,H]
               const float* __restrict__ bih0,
               const float* __restrict__ bhh0,
               const float* __restrict__ Wih1,  // [4H,H]
               const float* __restrict__ Whh1,  // [4H,H]
               const float* __restrict__ bih1,
               const float* __restrict__ bhh1,
               const float* __restrict__ fcw,   // [1,H]
               const float* __restrict__ fcb,   // [1]
               float* __restrict__ out,         // [B]
               int T, int B)
{
    const int tid  = threadIdx.x;
    const int w    = tid >> 6;         // wave 0..3: owns hidden rows 16w..16w+16 of each gate
    const int lane = tid & 63;
    const int bcol = lane & 15;        // MFMA column = batch
    const int hi4  = lane >> 4;        // k-group / row-group
    const int b0   = blockIdx.x * NB;

    __shared__ alignas(16) unsigned short xh[NB][XS],  xl[NB][XS];
    __shared__ alignas(16) unsigned short h0h[2][NB][HS], h0l[2][NB][HS];
    __shared__ alignas(16) unsigned short h1h[NB][HS], h1l[NB][HS];

    // ---- weight A-fragments (registers, loop-invariant) ----
    s8v wih0h[4], wih0l[4];
    s8v whh0h[4][2], whh0l[4][2];
    s8v wih1h[4][2], wih1l[4][2];
    s8v whh1h[4][2], whh1l[4][2];
    f4v bias0[4], bias1[4];
    #pragma unroll
    for (int g = 0; g < 4; ++g) {
        const int R = 64 * g + 16 * w + (lane & 15);   // A row for this lane
        load_frag(&Wih0[R * F], 8 * hi4, wih0h[g], wih0l[g]);
        #pragma unroll
        for (int kt = 0; kt < 2; ++kt) {
            load_frag(&Whh0[R * H], 32 * kt + 8 * hi4, whh0h[g][kt], whh0l[g][kt]);
            load_frag(&Wih1[R * H], 32 * kt + 8 * hi4, wih1h[g][kt], wih1l[g][kt]);
            load_frag(&Whh1[R * H], 32 * kt + 8 * hi4, whh1h[g][kt], whh1l[g][kt]);
        }
        const int RB = 64 * g + 16 * w + 4 * hi4;      // C rows for this lane
        #pragma unroll
        for (int r = 0; r < 4; ++r) {
            bias0[g][r] = bih0[RB + r] + bhh0[RB + r];
            bias1[g][r] = bih1[RB + r] + bhh1[RB + r];
        }
    }

    // ---- init LDS: h=0 everywhere, stage x(t=0) ----
    for (int i = tid; i < 2 * NB * HS; i += NT) { (&h0h[0][0][0])[i] = 0; (&h0l[0][0][0])[i] = 0; }
    for (int i = tid; i < NB * HS; i += NT)     { (&h1h[0][0])[i] = 0;    (&h1l[0][0])[i] = 0; }
    const int xb = tid >> 4;          // batch for x staging
    const int xk = 2 * (tid & 15);    // k pair for x staging
    {
        const float2 v = *(const float2*)&x[((size_t)(b0 + xb) * T + 0) * F + xk];
        ushort2 ph, pl;
        unsigned short a = f2bf(v.x); ph.x = a; pl.x = f2bf(v.x - bf2f(a));
        unsigned short b = f2bf(v.y); ph.y = b; pl.y = f2bf(v.y - bf2f(b));
        *(ushort2*)&xh[xb][xk] = ph;
        *(ushort2*)&xl[xb][xk] = pl;
    }
    __syncthreads();

    f4v c0 = {0.f, 0.f, 0.f, 0.f};
    f4v c1 = {0.f, 0.f, 0.f, 0.f};
    const int j0 = 16 * w + 4 * hi4;  // first hidden row this lane owns

    #pragma unroll 1
    for (int t = 0; t < T; ++t) {
        const int cur = t & 1, prv = cur ^ 1;

        // prefetch x(t+1) from HBM (consumed at end of step)
        float2 xpre = {0.f, 0.f};
        if (t + 1 < T)
            xpre = *(const float2*)&x[((size_t)(b0 + xb) * T + (t + 1)) * F + xk];

        // ---- B-fragments available at step start ----
        s8v xfh = *(const s8v*)&xh[bcol][8 * hi4];
        s8v xfl = *(const s8v*)&xl[bcol][8 * hi4];
        s8v h0fh[2], h0fl[2], h1fh[2], h1fl[2];
        #pragma unroll
        for (int kt = 0; kt < 2; ++kt) {
            h0fh[kt] = *(const s8v*)&h0h[prv][bcol][32 * kt + 8 * hi4];
            h0fl[kt] = *(const s8v*)&h0l[prv][bcol][32 * kt + 8 * hi4];
            h1fh[kt] = *(const s8v*)&h1h[bcol][32 * kt + 8 * hi4];
            h1fl[kt] = *(const s8v*)&h1l[bcol][32 * kt + 8 * hi4];
        }

        // ---- gates0 = bias0 + Wih0@x + Whh0@h0(t-1)  (3-term split bf16) ----
        f4v acc0[4];
        #pragma unroll
        for (int g = 0; g < 4; ++g) {
            f4v a = bias0[g];
            a = mfma_(wih0h[g], xfh, a);
            a = mfma_(wih0h[g], xfl, a);
            a = mfma_(wih0l[g], xfh, a);
            #pragma unroll
            for (int kt = 0; kt < 2; ++kt) {
                a = mfma_(whh0h[g][kt], h0fh[kt], a);
                a = mfma_(whh0h[g][kt], h0fl[kt], a);
                a = mfma_(whh0l[g][kt], h0fh[kt], a);
            }
            acc0[g] = a;
        }
        // ---- partial gates1 = bias1 + Whh1@h1(t-1)  (independent of h0(t)) ----
        f4v acc1[4];
        #pragma unroll
        for (int g = 0; g < 4; ++g) {
            f4v a = bias1[g];
            #pragma unroll
            for (int kt = 0; kt < 2; ++kt) {
                a = mfma_(whh1h[g][kt], h1fh[kt], a);
                a = mfma_(whh1h[g][kt], h1fl[kt], a);
                a = mfma_(whh1l[g][kt], h1fh[kt], a);
            }
            acc1[g] = a;
        }

        // ---- pointwise layer 0 -> h0(t) ----
        {
            ushort4 ph, pl;
            #pragma unroll
            for (int r = 0; r < 4; ++r) {
                float iv = sig_(acc0[0][r]);
                float fv = sig_(acc0[1][r]);
                float gv = tanh_(acc0[2][r]);
                float ov = sig_(acc0[3][r]);
                c0[r] = fv * c0[r] + iv * gv;
                float hv = ov * tanh_(c0[r]);
                unsigned short hh = f2bf(hv);
                (&ph.x)[r] = hh;
                (&pl.x)[r] = f2bf(hv - bf2f(hh));
            }
            *(ushort4*)&h0h[cur][bcol][j0] = ph;
            *(ushort4*)&h0l[cur][bcol][j0] = pl;
        }
        __syncthreads();   // barrier 1: h0(t) visible; x(t)/h-frag reads done

        // ---- finish gates1 += Wih1@h0(t) ----
        s8v g0fh[2], g0fl[2];
        #pragma unroll
        for (int kt = 0; kt < 2; ++kt) {
            g0fh[kt] = *(const s8v*)&h0h[cur][bcol][32 * kt + 8 * hi4];
            g0fl[kt] = *(const s8v*)&h0l[cur][bcol][32 * kt + 8 * hi4];
        }
        #pragma unroll
        for (int g = 0; g < 4; ++g) {
            f4v a = acc1[g];
            #pragma unroll
            for (int kt = 0; kt < 2; ++kt) {
                a = mfma_(wih1h[g][kt], g0fh[kt], a);
                a = mfma_(wih1h[g][kt], g0fl[kt], a);
                a = mfma_(wih1l[g][kt], g0fh[kt], a);
            }
            acc1[g] = a;
        }
        // ---- pointwise layer 1 -> h1(t) ----
        {
            ushort4 ph, pl;
            #pragma unroll
            for (int r = 0; r < 4; ++r) {
                float iv = sig_(acc1[0][r]);
                float fv = sig_(acc1[1][r]);
                float gv = tanh_(acc1[2][r]);
                float ov = sig_(acc1[3][r]);
                c1[r] = fv * c1[r] + iv * gv;
                float hv = ov * tanh_(c1[r]);
                unsigned short hh = f2bf(hv);
                (&ph.x)[r] = hh;
                (&pl.x)[r] = f2bf(hv - bf2f(hh));
            }
            *(ushort4*)&h1h[bcol][j0] = ph;
            *(ushort4*)&h1l[bcol][j0] = pl;
        }
        // ---- stage x(t+1) (x(t) readers finished before barrier 1) ----
        if (t + 1 < T) {
            ushort2 ph, pl;
            unsigned short a = f2bf(xpre.x); ph.x = a; pl.x = f2bf(xpre.x - bf2f(a));
            unsigned short b = f2bf(xpre.y); ph.y = b; pl.y = f2bf(xpre.y - bf2f(b));
            *(ushort2*)&xh[xb][xk] = ph;
            *(ushort2*)&xl[xb][xk] = pl;
        }
        __syncthreads();   // barrier 2: h1(t), x(t+1) visible
    }

    // ---- fc head: out[b] = sum_j h1[T-1][b][j]*fcw[j] + fcb ----
    if (tid < 64) {
        float s = 0.f;
        #pragma unroll
        for (int j = 0; j < 16; ++j) {
            const int jj = 16 * hi4 + j;
            s += (bf2f(h1h[bcol][jj]) + bf2f(h1l[bcol][jj])) * fcw[jj];
        }
        s += __shfl_xor(s, 16);
        s += __shfl_xor(s, 32);
        if (hi4 == 0) out[b0 + bcol] = s + fcb[0];
    }
}

extern "C" void kernel_launch(void* const* d_in, const int* in_sizes, int n_in,
                              void* d_out, int out_size, void* d_ws, size_t ws_size,
                              hipStream_t stream) {
    const float* x    = (const float*)d_in[0];
    const float* Wih0 = (const float*)d_in[1];
    const float* Whh0 = (const float*)d_in[2];
    const float* bih0 = (const float*)d_in[3];
    const float* bhh0 = (const float*)d_in[4];
    const float* Wih1 = (const float*)d_in[5];
    const float* Whh1 = (const float*)d_in[6];
    const float* bih1 = (const float*)d_in[7];
    const float* bhh1 = (const float*)d_in[8];
    const float* fcw  = (const float*)d_in[9];
    const float* fcb  = (const float*)d_in[10];
    float* out = (float*)d_out;

    const int B = out_size;                 // 1024
    const int T = in_sizes[0] / (B * F);    // 512

    dim3 grid(B / NB), block(NT);
    hipLaunchKernelGGL(lstm_mfma, grid, block, 0, stream,
                       x, Wih0, Whh0, bih0, bhh0,
                       Wih1, Whh1, bih1, bhh1, fcw, fcb,
                       out, T, B);
}

// Round 3
// 688.775 us; speedup vs baseline: 4.9050x; 1.1779x over previous
//
#include <hip/hip_runtime.h>
#include <math.h>

#define H  64
#define F  32
#define NB 16     // batch columns per block (= MFMA N)
#define NT 512    // 8 waves: 0-3 = layer0, 4-7 = layer1
#define XS 40     // LDS row stride (shorts) for x arrays (padded, conflict-free)

typedef __attribute__((ext_vector_type(8))) short   s8v;   // 8 bf16 payload
typedef __attribute__((ext_vector_type(8))) __bf16  bf8v;  // MFMA operand type
typedef __attribute__((ext_vector_type(4))) float   f4v;   // MFMA accumulator

__device__ __forceinline__ unsigned short f2bf(float x) {
    unsigned u = __builtin_bit_cast(unsigned, x);
    u += 0x7FFFu + ((u >> 16) & 1u);          // RNE
    return (unsigned short)(u >> 16);
}
__device__ __forceinline__ float bf2f(unsigned short h) {
    unsigned u = ((unsigned)h) << 16;
    return __builtin_bit_cast(float, u);
}
__device__ __forceinline__ f4v mfma_(s8v a, s8v b, f4v c) {
    return __builtin_amdgcn_mfma_f32_16x16x32_bf16(
        __builtin_bit_cast(bf8v, a), __builtin_bit_cast(bf8v, b), c, 0, 0, 0);
}
__device__ __forceinline__ float sig_(float x) {
    return __builtin_amdgcn_rcpf(1.0f + __expf(-x));
}
__device__ __forceinline__ float tanh_(float x) {
    return 1.0f - 2.0f * __builtin_amdgcn_rcpf(1.0f + __expf(2.0f * x));
}

// Load an 8-wide A-fragment slice of a weight row, split hi/lo bf16.
__device__ __forceinline__ void load_frag(const float* __restrict__ Wrow, int koff,
                                          s8v& hi, s8v& lo) {
    #pragma unroll
    for (int i = 0; i < 8; ++i) {
        float v = Wrow[koff + i];
        unsigned short h = f2bf(v);
        hi[i] = (short)h;
        lo[i] = (short)f2bf(v - bf2f(h));
    }
}

// ---- XOR-swizzled h-tile access: rows of 64 shorts = 8 slots of 16B ----
// phys_slot = logical_slot ^ (row & 7)  -> each 16-lane read group spreads
// over 8 slot-quads (2 rows each) = conflict-free ds_read_b128.
__device__ __forceinline__ s8v ld_h(const unsigned short (*buf)[64], int b, int slot) {
    const int phys = slot ^ (b & 7);
    return *(const s8v*)&buf[b][phys * 8];
}
__device__ __forceinline__ void st_h(unsigned short (*buf)[64], int b, int j0, ushort4 v) {
    const int phys = (j0 >> 3) ^ (b & 7);
    *(ushort4*)&buf[b][phys * 8 + (j0 & 7)] = v;
}

__global__ __launch_bounds__(NT, 2)
void lstm_pipe(const float* __restrict__ x,     // [B,T,F]
               const float* __restrict__ Wih0,  // [4H,F]
               const float* __restrict__ Whh0,  // [4H,H]
               const float* __restrict__ bih0,
               const float* __restrict__ bhh0,
               const float* __restrict__ Wih1,  // [4H,H]
               const float* __restrict__ Whh1,  // [4H,H]
               const float* __restrict__ bih1,
               const float* __restrict__ bhh1,
               const float* __restrict__ fcw,   // [1,H]
               const float* __restrict__ fcb,   // [1]
               float* __restrict__ out,         // [B]
               int T, int B)
{
    const int tid  = threadIdx.x;
    const int w    = tid >> 6;         // 0..7
    const int wl   = w & 3;            // wave within its layer-group
    const bool isL0 = (w < 4);
    const int lane = tid & 63;
    const int bcol = lane & 15;        // MFMA column = batch
    const int hi4  = lane >> 4;        // k-group / row-group
    const int b0   = blockIdx.x * NB;

    __shared__ alignas(16) unsigned short xh[2][NB][XS], xl[2][NB][XS];
    __shared__ alignas(16) unsigned short h0h[2][NB][64], h0l[2][NB][64];
    __shared__ alignas(16) unsigned short h1h[2][NB][64], h1l[2][NB][64];

    // ---- weight A-fragments, register overlay shared by both groups ----
    // L0: wreg[g]=Wih0_hi, wreg[4+g]=Wih0_lo, wreg[8+2g+kt]=Whh0_hi, wreg[16+2g+kt]=Whh0_lo
    // L1: wreg[2g+kt]=Wih1_hi, wreg[8+2g+kt]=Wih1_lo, wreg[16+2g+kt]=Whh1_hi, wreg[24+2g+kt]=Whh1_lo
    s8v wreg[32];
    f4v bias[4];
    if (isL0) {
        #pragma unroll
        for (int g = 0; g < 4; ++g) {
            const int R = 64 * g + 16 * wl + bcol;
            load_frag(&Wih0[R * F], 8 * hi4, wreg[g], wreg[4 + g]);
            #pragma unroll
            for (int kt = 0; kt < 2; ++kt)
                load_frag(&Whh0[R * H], 32 * kt + 8 * hi4, wreg[8 + 2 * g + kt], wreg[16 + 2 * g + kt]);
            const int RB = 64 * g + 16 * wl + 4 * hi4;
            #pragma unroll
            for (int r = 0; r < 4; ++r) bias[g][r] = bih0[RB + r] + bhh0[RB + r];
        }
        #pragma unroll
        for (int g = 0; g < 4; ++g) { wreg[24 + g] = wreg[g]; wreg[28 + g] = wreg[g]; } // keep defined
    } else {
        #pragma unroll
        for (int g = 0; g < 4; ++g) {
            const int R = 64 * g + 16 * wl + bcol;
            #pragma unroll
            for (int kt = 0; kt < 2; ++kt) {
                load_frag(&Wih1[R * H], 32 * kt + 8 * hi4, wreg[2 * g + kt], wreg[8 + 2 * g + kt]);
                load_frag(&Whh1[R * H], 32 * kt + 8 * hi4, wreg[16 + 2 * g + kt], wreg[24 + 2 * g + kt]);
            }
            const int RB = 64 * g + 16 * wl + 4 * hi4;
            #pragma unroll
            for (int r = 0; r < 4; ++r) bias[g][r] = bih1[RB + r] + bhh1[RB + r];
        }
    }

    // ---- init LDS (zero h buffers), stage x(0) into xbuf[0] ----
    for (int i = tid; i < 2 * NB * 64; i += NT) {
        (&h0h[0][0][0])[i] = 0; (&h0l[0][0][0])[i] = 0;
        (&h1h[0][0][0])[i] = 0; (&h1l[0][0][0])[i] = 0;
    }
    const int xb = tid >> 4;          // 0..15 for tid<256
    const int xk = 2 * (tid & 15);
    if (tid < 256) {
        const float2 v = *(const float2*)&x[((size_t)(b0 + xb) * T + 0) * F + xk];
        ushort2 qh, ql;
        unsigned short a1 = f2bf(v.x); qh.x = a1; ql.x = f2bf(v.x - bf2f(a1));
        unsigned short a2 = f2bf(v.y); qh.y = a2; ql.y = f2bf(v.y - bf2f(a2));
        *(ushort2*)&xh[0][xb][xk] = qh;
        *(ushort2*)&xl[0][xb][xk] = ql;
    }
    __syncthreads();

    f4v cst = {0.f, 0.f, 0.f, 0.f};     // c0 for L0 lanes, c1 for L1 lanes
    const int j0 = 16 * wl + 4 * hi4;   // first hidden row this lane owns

    #pragma unroll 1
    for (int s = 0; s <= T; ++s) {
        const int par = s & 1;
        if (isL0) {
            if (s < T) {
                // prefetch x(s+1)
                float2 xpre = {0.f, 0.f};
                if (s + 1 < T)
                    xpre = *(const float2*)&x[((size_t)(b0 + xb) * T + (s + 1)) * F + xk];

                s8v xfh = *(const s8v*)&xh[par][bcol][8 * hi4];
                s8v xfl = *(const s8v*)&xl[par][bcol][8 * hi4];
                s8v hfh[2], hfl[2];
                #pragma unroll
                for (int kt = 0; kt < 2; ++kt) {
                    hfh[kt] = ld_h(h0h[par ^ 1], bcol, 4 * kt + hi4);
                    hfl[kt] = ld_h(h0l[par ^ 1], bcol, 4 * kt + hi4);
                }
                f4v acc[4], accB[4];
                #pragma unroll
                for (int g = 0; g < 4; ++g) {
                    f4v a = bias[g];
                    a = mfma_(wreg[g],     xfh, a);
                    a = mfma_(wreg[g],     xfl, a);
                    a = mfma_(wreg[4 + g], xfh, a);
                    acc[g] = a;
                    f4v bacc = {0.f, 0.f, 0.f, 0.f};
                    #pragma unroll
                    for (int kt = 0; kt < 2; ++kt) {
                        bacc = mfma_(wreg[8 + 2 * g + kt],  hfh[kt], bacc);
                        bacc = mfma_(wreg[8 + 2 * g + kt],  hfl[kt], bacc);
                        bacc = mfma_(wreg[16 + 2 * g + kt], hfh[kt], bacc);
                    }
                    accB[g] = bacc;
                }
                ushort4 ph, pl;
                #pragma unroll
                for (int r = 0; r < 4; ++r) {
                    float gi = sig_(acc[0][r] + accB[0][r]);
                    float gf = sig_(acc[1][r] + accB[1][r]);
                    float gg = tanh_(acc[2][r] + accB[2][r]);
                    float go = sig_(acc[3][r] + accB[3][r]);
                    cst[r] = gf * cst[r] + gi * gg;
                    float hv = go * tanh_(cst[r]);
                    unsigned short hh = f2bf(hv);
                    (&ph.x)[r] = hh;
                    (&pl.x)[r] = f2bf(hv - bf2f(hh));
                }
                st_h(h0h[par], bcol, j0, ph);
                st_h(h0l[par], bcol, j0, pl);
                if (s + 1 < T) {
                    ushort2 qh, ql;
                    unsigned short a1 = f2bf(xpre.x); qh.x = a1; ql.x = f2bf(xpre.x - bf2f(a1));
                    unsigned short a2 = f2bf(xpre.y); qh.y = a2; ql.y = f2bf(xpre.y - bf2f(a2));
                    *(ushort2*)&xh[par ^ 1][xb][xk] = qh;
                    *(ushort2*)&xl[par ^ 1][xb][xk] = ql;
                }
            }
        } else {
            if (s >= 1) {
                // layer 1 computes t = s-1: inputs h0(s-1) [buf par^1], h1(s-2) [buf par]
                s8v gfh[2], gfl[2], hfh[2], hfl[2];
                #pragma unroll
                for (int kt = 0; kt < 2; ++kt) {
                    gfh[kt] = ld_h(h0h[par ^ 1], bcol, 4 * kt + hi4);
                    gfl[kt] = ld_h(h0l[par ^ 1], bcol, 4 * kt + hi4);
                    hfh[kt] = ld_h(h1h[par],     bcol, 4 * kt + hi4);
                    hfl[kt] = ld_h(h1l[par],     bcol, 4 * kt + hi4);
                }
                f4v acc[4], accB[4];
                #pragma unroll
                for (int g = 0; g < 4; ++g) {
                    f4v a = bias[g];
                    #pragma unroll
                    for (int kt = 0; kt < 2; ++kt) {
                        a = mfma_(wreg[16 + 2 * g + kt], hfh[kt], a);
                        a = mfma_(wreg[16 + 2 * g + kt], hfl[kt], a);
                        a = mfma_(wreg[24 + 2 * g + kt], hfh[kt], a);
                    }
                    acc[g] = a;
                    f4v bacc = {0.f, 0.f, 0.f, 0.f};
                    #pragma unroll
                    for (int kt = 0; kt < 2; ++kt) {
                        bacc = mfma_(wreg[2 * g + kt],     gfh[kt], bacc);
                        bacc = mfma_(wreg[2 * g + kt],     gfl[kt], bacc);
                        bacc = mfma_(wreg[8 + 2 * g + kt], gfh[kt], bacc);
                    }
                    accB[g] = bacc;
                }
                ushort4 ph, pl;
                #pragma unroll
                for (int r = 0; r < 4; ++r) {
                    float gi = sig_(acc[0][r] + accB[0][r]);
                    float gf = sig_(acc[1][r] + accB[1][r]);
                    float gg = tanh_(acc[2][r] + accB[2][r]);
                    float go = sig_(acc[3][r] + accB[3][r]);
                    cst[r] = gf * cst[r] + gi * gg;
                    float hv = go * tanh_(cst[r]);
                    unsigned short hh = f2bf(hv);
                    (&ph.x)[r] = hh;
                    (&pl.x)[r] = f2bf(hv - bf2f(hh));
                }
                st_h(h1h[par ^ 1], bcol, j0, ph);
                st_h(h1l[par ^ 1], bcol, j0, pl);
            }
        }
        __syncthreads();
    }

    // ---- fc head: out[b] = sum_j h1[T-1][b][j]*fcw[j] + fcb ----
    if (tid < 64) {
        const int fb = (T & 1) ^ 1;     // buffer holding h1(T-1)
        float sacc = 0.f;
        #pragma unroll
        for (int j = 0; j < 16; ++j) {
            const int jj = 16 * hi4 + j;
            const int ph = ((jj >> 3) ^ (bcol & 7)) * 8 + (jj & 7);
            sacc += (bf2f(h1h[fb][bcol][ph]) + bf2f(h1l[fb][bcol][ph])) * fcw[jj];
        }
        sacc += __shfl_xor(sacc, 16);
        sacc += __shfl_xor(sacc, 32);
        if (hi4 == 0) out[b0 + bcol] = sacc + fcb[0];
    }
}

extern "C" void kernel_launch(void* const* d_in, const int* in_sizes, int n_in,
                              void* d_out, int out_size, void* d_ws, size_t ws_size,
                              hipStream_t stream) {
    const float* x    = (const float*)d_in[0];
    const float* Wih0 = (const float*)d_in[1];
    const float* Whh0 = (const float*)d_in[2];
    const float* bih0 = (const float*)d_in[3];
    const float* bhh0 = (const float*)d_in[4];
    const float* Wih1 = (const float*)d_in[5];
    const float* Whh1 = (const float*)d_in[6];
    const float* bih1 = (const float*)d_in[7];
    const float* bhh1 = (const float*)d_in[8];
    const float* fcw  = (const float*)d_in[9];
    const float* fcb  = (const float*)d_in[10];
    float* out = (float*)d_out;

    const int B = out_size;                 // 1024
    const int T = in_sizes[0] / (B * F);    // 512

    dim3 grid(B / NB), block(NT);
    hipLaunchKernelGGL(lstm_pipe, grid, block, 0, stream,
                       x, Wih0, Whh0, bih0, bhh0,
                       Wih1, Whh1, bih1, bhh1, fcw, fcb,
                       out, T, B);
}

// Round 4
// 562.174 us; speedup vs baseline: 6.0096x; 1.2252x over previous
//
#include <hip/hip_runtime.h>
#include <math.h>

#define H  64
#define F  32
#define NB 16     // batch columns per block (= MFMA N)
#define NT 512    // 8 waves: 0-3 = layer0, 4-7 = layer1 (wave-specialized loops)
#define XS 40     // LDS row stride (shorts) for x arrays

typedef __attribute__((ext_vector_type(8))) short   s8v;   // 8 bf16 payload
typedef __attribute__((ext_vector_type(8))) __bf16  bf8v;  // MFMA operand type
typedef __attribute__((ext_vector_type(4))) float   f4v;   // MFMA accumulator

__device__ __forceinline__ unsigned short f2bf(float x) {
    unsigned u = __builtin_bit_cast(unsigned, x);
    u += 0x7FFFu + ((u >> 16) & 1u);          // RNE
    return (unsigned short)(u >> 16);
}
__device__ __forceinline__ float bf2f(unsigned short h) {
    unsigned u = ((unsigned)h) << 16;
    return __builtin_bit_cast(float, u);
}
__device__ __forceinline__ f4v mfma_(s8v a, s8v b, f4v c) {
    return __builtin_amdgcn_mfma_f32_16x16x32_bf16(
        __builtin_bit_cast(bf8v, a), __builtin_bit_cast(bf8v, b), c, 0, 0, 0);
}
__device__ __forceinline__ float sig_(float x) {
    return __builtin_amdgcn_rcpf(1.0f + __expf(-x));
}
__device__ __forceinline__ float tanh_(float x) {
    return 1.0f - 2.0f * __builtin_amdgcn_rcpf(1.0f + __expf(2.0f * x));
}

// Load an 8-wide A-fragment slice of a weight row, split hi/lo bf16.
__device__ __forceinline__ void load_frag(const float* __restrict__ Wrow, int koff,
                                          s8v& hi, s8v& lo) {
    #pragma unroll
    for (int i = 0; i < 8; ++i) {
        float v = Wrow[koff + i];
        unsigned short h = f2bf(v);
        hi[i] = (short)h;
        lo[i] = (short)f2bf(v - bf2f(h));
    }
}

// ---- XOR-swizzled h-tile access: rows of 64 shorts = 8 slots of 16B ----
__device__ __forceinline__ s8v ld_h(const unsigned short (*buf)[64], int b, int slot) {
    const int phys = slot ^ (b & 7);
    return *(const s8v*)&buf[b][phys * 8];
}
__device__ __forceinline__ void st_h(unsigned short (*buf)[64], int b, int j0, ushort4 v) {
    const int phys = (j0 >> 3) ^ (b & 7);
    *(ushort4*)&buf[b][phys * 8 + (j0 & 7)] = v;
}

__global__ __launch_bounds__(NT, 2)
void lstm_ws(const float* __restrict__ x,     // [B,T,F]
             const float* __restrict__ Wih0,  // [4H,F]
             const float* __restrict__ Whh0,  // [4H,H]
             const float* __restrict__ bih0,
             const float* __restrict__ bhh0,
             const float* __restrict__ Wih1,  // [4H,H]
             const float* __restrict__ Whh1,  // [4H,H]
             const float* __restrict__ bih1,
             const float* __restrict__ bhh1,
             const float* __restrict__ fcw,   // [1,H]
             const float* __restrict__ fcb,   // [1]
             float* __restrict__ out,         // [B]
             int T, int B)
{
    const int tid  = threadIdx.x;
    const int w    = tid >> 6;         // 0..7
    const int wl   = w & 3;            // wave within its layer-group
    const bool isL0 = (w < 4);
    const int lane = tid & 63;
    const int bcol = lane & 15;        // MFMA column = batch
    const int hi4  = lane >> 4;        // k-group / row-group
    const int b0   = blockIdx.x * NB;
    const int j0   = 16 * wl + 4 * hi4;

    __shared__ alignas(16) unsigned short xh[2][NB][XS], xl[2][NB][XS];
    __shared__ alignas(16) unsigned short h0[2][NB][64];   // bf16-hi only
    __shared__ alignas(16) unsigned short h1[2][NB][64];   // bf16-hi only
    __shared__ float part[4][4][NB];                       // fc-head partials

    // zero h buffers (h(-1) = 0)
    for (int i = tid; i < 2 * NB * 64; i += NT) {
        (&h0[0][0][0])[i] = 0;
        (&h1[0][0][0])[i] = 0;
    }

    if (isL0) {
        // ================= LAYER-0 WAVES =================
        s8v wxh[4], wxl[4];          // Wih0 hi/lo (K=32: one k-tile)
        s8v whh[4][2], whl[4][2];    // Whh0 hi/lo (2 k-tiles)
        f4v bias[4];
        #pragma unroll
        for (int g = 0; g < 4; ++g) {
            const int R = 64 * g + 16 * wl + bcol;
            load_frag(&Wih0[R * F], 8 * hi4, wxh[g], wxl[g]);
            #pragma unroll
            for (int kt = 0; kt < 2; ++kt)
                load_frag(&Whh0[R * H], 32 * kt + 8 * hi4, whh[g][kt], whl[g][kt]);
            const int RB = 64 * g + 16 * wl + 4 * hi4;
            #pragma unroll
            for (int r = 0; r < 4; ++r) bias[g][r] = bih0[RB + r] + bhh0[RB + r];
        }
        // stage x(0): 256 L0 threads, 2 floats each
        const int xb = tid >> 4, xk = 2 * (tid & 15);
        {
            const float2 v = *(const float2*)&x[((size_t)(b0 + xb) * T + 0) * F + xk];
            ushort2 qh, ql;
            unsigned short a1 = f2bf(v.x); qh.x = a1; ql.x = f2bf(v.x - bf2f(a1));
            unsigned short a2 = f2bf(v.y); qh.y = a2; ql.y = f2bf(v.y - bf2f(a2));
            *(ushort2*)&xh[0][xb][xk] = qh;
            *(ushort2*)&xl[0][xb][xk] = ql;
        }
        __syncthreads();   // prolog barrier

        f4v c = {0.f, 0.f, 0.f, 0.f};
        #pragma unroll 1
        for (int s = 0; s <= T; ++s) {
            const int par = s & 1;
            if (s < T) {
                float2 xpre = {0.f, 0.f};
                if (s + 1 < T)
                    xpre = *(const float2*)&x[((size_t)(b0 + xb) * T + (s + 1)) * F + xk];

                const s8v xfh = *(const s8v*)&xh[par][bcol][8 * hi4];
                const s8v xfl = *(const s8v*)&xl[par][bcol][8 * hi4];
                const s8v hf0 = ld_h(h0[par ^ 1], bcol, hi4);
                const s8v hf1 = ld_h(h0[par ^ 1], bcol, 4 + hi4);

                f4v accA[4], accB[4];
                #pragma unroll
                for (int g = 0; g < 4; ++g) {
                    f4v a = bias[g];
                    a = mfma_(wxh[g], xfh, a);
                    a = mfma_(wxh[g], xfl, a);
                    a = mfma_(wxl[g], xfh, a);
                    accA[g] = a;
                    f4v b = {0.f, 0.f, 0.f, 0.f};
                    b = mfma_(whh[g][0], hf0, b);
                    b = mfma_(whl[g][0], hf0, b);
                    b = mfma_(whh[g][1], hf1, b);
                    b = mfma_(whl[g][1], hf1, b);
                    accB[g] = b;
                }
                ushort4 ph;
                #pragma unroll
                for (int r = 0; r < 4; ++r) {
                    float gi = sig_(accA[0][r] + accB[0][r]);
                    float gf = sig_(accA[1][r] + accB[1][r]);
                    float gg = tanh_(accA[2][r] + accB[2][r]);
                    float go = sig_(accA[3][r] + accB[3][r]);
                    c[r] = gf * c[r] + gi * gg;
                    (&ph.x)[r] = f2bf(go * tanh_(c[r]));
                }
                st_h(h0[par], bcol, j0, ph);

                if (s + 1 < T) {
                    ushort2 qh, ql;
                    unsigned short a1 = f2bf(xpre.x); qh.x = a1; ql.x = f2bf(xpre.x - bf2f(a1));
                    unsigned short a2 = f2bf(xpre.y); qh.y = a2; ql.y = f2bf(xpre.y - bf2f(a2));
                    *(ushort2*)&xh[par ^ 1][xb][xk] = qh;
                    *(ushort2*)&xl[par ^ 1][xb][xk] = ql;
                }
            }
            __syncthreads();
        }
    } else {
        // ================= LAYER-1 WAVES =================
        s8v wgh[4][2], wgl[4][2];    // Wih1 hi/lo
        s8v whh[4][2], whl[4][2];    // Whh1 hi/lo
        f4v bias[4];
        float fcwr[4];
        #pragma unroll
        for (int g = 0; g < 4; ++g) {
            const int R = 64 * g + 16 * wl + bcol;
            #pragma unroll
            for (int kt = 0; kt < 2; ++kt) {
                load_frag(&Wih1[R * H], 32 * kt + 8 * hi4, wgh[g][kt], wgl[g][kt]);
                load_frag(&Whh1[R * H], 32 * kt + 8 * hi4, whh[g][kt], whl[g][kt]);
            }
            const int RB = 64 * g + 16 * wl + 4 * hi4;
            #pragma unroll
            for (int r = 0; r < 4; ++r) bias[g][r] = bih1[RB + r] + bhh1[RB + r];
        }
        #pragma unroll
        for (int r = 0; r < 4; ++r) fcwr[r] = fcw[j0 + r];
        __syncthreads();   // prolog barrier

        f4v c = {0.f, 0.f, 0.f, 0.f};
        #pragma unroll 1
        for (int s = 0; s <= T; ++s) {
            const int par = s & 1;
            if (s >= 1) {
                // computes t = s-1: inputs h0(s-1) [buf par^1], h1(s-2) [buf par]
                const s8v gf0 = ld_h(h0[par ^ 1], bcol, hi4);
                const s8v gf1 = ld_h(h0[par ^ 1], bcol, 4 + hi4);
                const s8v hf0 = ld_h(h1[par],     bcol, hi4);
                const s8v hf1 = ld_h(h1[par],     bcol, 4 + hi4);

                f4v accA[4], accB[4];
                #pragma unroll
                for (int g = 0; g < 4; ++g) {
                    f4v a = bias[g];
                    a = mfma_(wgh[g][0], gf0, a);
                    a = mfma_(wgl[g][0], gf0, a);
                    a = mfma_(wgh[g][1], gf1, a);
                    a = mfma_(wgl[g][1], gf1, a);
                    accA[g] = a;
                    f4v b = {0.f, 0.f, 0.f, 0.f};
                    b = mfma_(whh[g][0], hf0, b);
                    b = mfma_(whl[g][0], hf0, b);
                    b = mfma_(whh[g][1], hf1, b);
                    b = mfma_(whl[g][1], hf1, b);
                    accB[g] = b;
                }
                float hv[4];
                #pragma unroll
                for (int r = 0; r < 4; ++r) {
                    float gi = sig_(accA[0][r] + accB[0][r]);
                    float gf = sig_(accA[1][r] + accB[1][r]);
                    float gg = tanh_(accA[2][r] + accB[2][r]);
                    float go = sig_(accA[3][r] + accB[3][r]);
                    c[r] = gf * c[r] + gi * gg;
                    hv[r] = go * tanh_(c[r]);
                }
                if (s < T) {
                    ushort4 ph;
                    #pragma unroll
                    for (int r = 0; r < 4; ++r) (&ph.x)[r] = f2bf(hv[r]);
                    st_h(h1[par ^ 1], bcol, j0, ph);
                } else {
                    // final step: fc-head partial from fp32 h
                    part[wl][hi4][bcol] =
                        hv[0] * fcwr[0] + hv[1] * fcwr[1] + hv[2] * fcwr[2] + hv[3] * fcwr[3];
                }
            }
            __syncthreads();
        }
    }

    // ---- fc head: out[b] = sum over (wl, hi4) partials + fcb ----
    if (tid < 64) {
        float s = part[0][hi4][bcol] + part[1][hi4][bcol]
                + part[2][hi4][bcol] + part[3][hi4][bcol];
        s += __shfl_xor(s, 16);
        s += __shfl_xor(s, 32);
        if (hi4 == 0) out[b0 + bcol] = s + fcb[0];
    }
}

extern "C" void kernel_launch(void* const* d_in, const int* in_sizes, int n_in,
                              void* d_out, int out_size, void* d_ws, size_t ws_size,
                              hipStream_t stream) {
    const float* x    = (const float*)d_in[0];
    const float* Wih0 = (const float*)d_in[1];
    const float* Whh0 = (const float*)d_in[2];
    const float* bih0 = (const float*)d_in[3];
    const float* bhh0 = (const float*)d_in[4];
    const float* Wih1 = (const float*)d_in[5];
    const float* Whh1 = (const float*)d_in[6];
    const float* bih1 = (const float*)d_in[7];
    const float* bhh1 = (const float*)d_in[8];
    const float* fcw  = (const float*)d_in[9];
    const float* fcb  = (const float*)d_in[10];
    float* out = (float*)d_out;

    const int B = out_size;                 // 1024
    const int T = in_sizes[0] / (B * F);    // 512

    dim3 grid(B / NB), block(NT);
    hipLaunchKernelGGL(lstm_ws, grid, block, 0, stream,
                       x, Wih0, Whh0, bih0, bhh0,
                       Wih1, Whh1, bih1, bhh1, fcw, fcb,
                       out, T, B);
}

// Round 5
// 451.847 us; speedup vs baseline: 7.4769x; 1.2442x over previous
//
#include <hip/hip_runtime.h>
#include <math.h>

#define H  64
#define F  32
#define NB 4      // batch columns per block (MFMA N=16, batch duplicated x4)
#define NT 512    // 8 waves: 0-3 = layer0, 4-7 = layer1 (wave-specialized)
#define XS 40     // LDS row stride (shorts) for x arrays

typedef __attribute__((ext_vector_type(8))) short   s8v;   // 8 bf16 payload
typedef __attribute__((ext_vector_type(8))) __bf16  bf8v;  // MFMA operand type
typedef __attribute__((ext_vector_type(4))) float   f4v;   // MFMA accumulator

__device__ __forceinline__ unsigned short f2bf(float x) {
    unsigned u = __builtin_bit_cast(unsigned, x);
    u += 0x7FFFu + ((u >> 16) & 1u);          // RNE
    return (unsigned short)(u >> 16);
}
__device__ __forceinline__ float bf2f(unsigned short h) {
    unsigned u = ((unsigned)h) << 16;
    return __builtin_bit_cast(float, u);
}
__device__ __forceinline__ f4v mfma_(s8v a, s8v b, f4v c) {
    return __builtin_amdgcn_mfma_f32_16x16x32_bf16(
        __builtin_bit_cast(bf8v, a), __builtin_bit_cast(bf8v, b), c, 0, 0, 0);
}
__device__ __forceinline__ float sig_(float x) {
    return __builtin_amdgcn_rcpf(1.0f + __expf(-x));
}
__device__ __forceinline__ float tanh_(float x) {
    return 1.0f - 2.0f * __builtin_amdgcn_rcpf(1.0f + __expf(2.0f * x));
}
// cross-lane: dest lane d reads src lane (d & 0x33)  [BitMode and-mask 0x13]
__device__ __forceinline__ float swz13(float v) {
    return __builtin_bit_cast(float,
        __builtin_amdgcn_ds_swizzle(__builtin_bit_cast(int, v), 0x0013));
}

// Load an 8-wide A-fragment slice of a weight row, split hi/lo bf16.
__device__ __forceinline__ void load_frag(const float* __restrict__ Wrow, int koff,
                                          s8v& hi, s8v& lo) {
    #pragma unroll
    for (int i = 0; i < 8; ++i) {
        float v = Wrow[koff + i];
        unsigned short h = f2bf(v);
        hi[i] = (short)h;
        lo[i] = (short)f2bf(v - bf2f(h));
    }
}

// ---- swizzled h-tile (4 rows x 64 shorts): phys_slot = slot ^ (b<<1) ----
__device__ __forceinline__ s8v ld_h(const unsigned short (*buf)[64], int b, int slot) {
    const int phys = slot ^ (b << 1);
    return *(const s8v*)&buf[b][phys * 8];
}
__device__ __forceinline__ void st_h16(unsigned short (*buf)[64], int b, int row,
                                       unsigned short v) {
    const int phys = ((row >> 3) ^ (b << 1)) * 8 + (row & 7);
    buf[b][phys] = v;
}

__global__ __launch_bounds__(NT, 2)
void lstm_nb4(const float* __restrict__ x,     // [B,T,F]
              const float* __restrict__ Wih0,  // [4H,F]
              const float* __restrict__ Whh0,  // [4H,H]
              const float* __restrict__ bih0,
              const float* __restrict__ bhh0,
              const float* __restrict__ Wih1,  // [4H,H]
              const float* __restrict__ Whh1,  // [4H,H]
              const float* __restrict__ bih1,
              const float* __restrict__ bhh1,
              const float* __restrict__ fcw,   // [1,H]
              const float* __restrict__ fcb,   // [1]
              float* __restrict__ out,         // [B]
              int T, int B)
{
    const int tid  = threadIdx.x;
    const int w    = tid >> 6;          // 0..7
    const int wl   = w & 3;             // wave within its layer group
    const bool isL0 = (w < 4);
    const int lane = tid & 63;
    const int bcol = lane & 15;         // MFMA column
    const int hi4  = lane >> 4;         // k-group / row-group
    const int bm   = bcol & 3;          // fragment batch (x4 duplication)
    const int rsel = (lane >> 2) & 3;   // which acc reg this lane's unit needs
    const int bu   = lane & 3;          // unit batch
    const int urow = 16 * wl + 4 * hi4 + rsel;   // unit hidden row
    const int b0   = blockIdx.x * NB;

    __shared__ alignas(16) unsigned short xh[2][NB][XS], xl[2][NB][XS];
    __shared__ alignas(16) unsigned short h0[2][NB][64];
    __shared__ alignas(16) unsigned short h1[2][NB][64];
    __shared__ float part[4][64];

    for (int i = tid; i < 2 * NB * 64; i += NT) {
        (&h0[0][0][0])[i] = 0;
        (&h1[0][0][0])[i] = 0;
    }

    if (isL0) {
        // ================= LAYER-0 WAVES =================
        s8v wxh[4], wxl[4];          // Wih0 hi/lo
        s8v whh[4][2], whl[4][2];    // Whh0 hi/lo
        f4v bias[4];
        #pragma unroll
        for (int g = 0; g < 4; ++g) {
            const int R = 64 * g + 16 * wl + bcol;
            load_frag(&Wih0[R * F], 8 * hi4, wxh[g], wxl[g]);
            #pragma unroll
            for (int kt = 0; kt < 2; ++kt)
                load_frag(&Whh0[R * H], 32 * kt + 8 * hi4, whh[g][kt], whl[g][kt]);
            const int RB = 64 * g + 16 * wl + 4 * hi4;
            #pragma unroll
            for (int r = 0; r < 4; ++r) bias[g][r] = bih0[RB + r] + bhh0[RB + r];
        }
        // stage x(0): 64 threads of wave 0, 2 floats each
        const int xb = tid >> 4, xk = 2 * (tid & 15);
        if (tid < 64) {
            const float2 v = *(const float2*)&x[((size_t)(b0 + xb) * T + 0) * F + xk];
            ushort2 qh, ql;
            unsigned short a1 = f2bf(v.x); qh.x = a1; ql.x = f2bf(v.x - bf2f(a1));
            unsigned short a2 = f2bf(v.y); qh.y = a2; ql.y = f2bf(v.y - bf2f(a2));
            *(ushort2*)&xh[0][xb][xk] = qh;
            *(ushort2*)&xl[0][xb][xk] = ql;
        }
        __syncthreads();   // prolog barrier

        float c = 0.f;
        #pragma unroll 1
        for (int s = 0; s <= T; ++s) {
            const int par = s & 1;
            if (s < T) {
                float2 xpre = {0.f, 0.f};
                if (tid < 64 && s + 1 < T)
                    xpre = *(const float2*)&x[((size_t)(b0 + xb) * T + (s + 1)) * F + xk];

                const s8v xfh = *(const s8v*)&xh[par][bm][8 * hi4];
                const s8v xfl = *(const s8v*)&xl[par][bm][8 * hi4];
                const s8v hf0 = ld_h(h0[par ^ 1], bm, hi4);
                const s8v hf1 = ld_h(h0[par ^ 1], bm, 4 + hi4);

                f4v acc[4];
                #pragma unroll
                for (int g = 0; g < 4; ++g) {
                    f4v a = bias[g];
                    a = mfma_(wxh[g], xfh, a);
                    a = mfma_(wxh[g], xfl, a);
                    a = mfma_(wxl[g], xfh, a);
                    f4v b = {0.f, 0.f, 0.f, 0.f};
                    b = mfma_(whh[g][0], hf0, b);
                    b = mfma_(whl[g][0], hf0, b);
                    b = mfma_(whh[g][1], hf1, b);
                    b = mfma_(whl[g][1], hf1, b);
                    acc[g] = a + b;
                }
                // redistribute: 1 unit per lane (all 4 gates)
                float g4[4];
                #pragma unroll
                for (int g = 0; g < 4; ++g) {
                    float t0 = swz13(acc[g][0]);
                    float t1 = swz13(acc[g][1]);
                    float t2 = swz13(acc[g][2]);
                    float t3 = swz13(acc[g][3]);
                    float s01 = (rsel & 1) ? t1 : t0;
                    float s23 = (rsel & 1) ? t3 : t2;
                    g4[g] = (rsel & 2) ? s23 : s01;
                }
                float gi = sig_(g4[0]);
                float gf = sig_(g4[1]);
                float gg = tanh_(g4[2]);
                float go = sig_(g4[3]);
                c = gf * c + gi * gg;
                const float hv = go * tanh_(c);
                st_h16(h0[par], bu, urow, f2bf(hv));

                if (tid < 64 && s + 1 < T) {
                    ushort2 qh, ql;
                    unsigned short a1 = f2bf(xpre.x); qh.x = a1; ql.x = f2bf(xpre.x - bf2f(a1));
                    unsigned short a2 = f2bf(xpre.y); qh.y = a2; ql.y = f2bf(xpre.y - bf2f(a2));
                    *(ushort2*)&xh[par ^ 1][xb][xk] = qh;
                    *(ushort2*)&xl[par ^ 1][xb][xk] = ql;
                }
            }
            __syncthreads();
        }
    } else {
        // ================= LAYER-1 WAVES =================
        s8v wgh[4][2], wgl[4][2];    // Wih1 hi/lo
        s8v whh[4][2], whl[4][2];    // Whh1 hi/lo
        f4v bias[4];
        #pragma unroll
        for (int g = 0; g < 4; ++g) {
            const int R = 64 * g + 16 * wl + bcol;
            #pragma unroll
            for (int kt = 0; kt < 2; ++kt) {
                load_frag(&Wih1[R * H], 32 * kt + 8 * hi4, wgh[g][kt], wgl[g][kt]);
                load_frag(&Whh1[R * H], 32 * kt + 8 * hi4, whh[g][kt], whl[g][kt]);
            }
            const int RB = 64 * g + 16 * wl + 4 * hi4;
            #pragma unroll
            for (int r = 0; r < 4; ++r) bias[g][r] = bih1[RB + r] + bhh1[RB + r];
        }
        const float fcwr = fcw[urow];
        __syncthreads();   // prolog barrier

        float c = 0.f;
        #pragma unroll 1
        for (int s = 0; s <= T; ++s) {
            const int par = s & 1;
            if (s >= 1) {
                // computes t = s-1: inputs h0(s-1) [buf par^1], h1(s-2) [buf par]
                const s8v gf0 = ld_h(h0[par ^ 1], bm, hi4);
                const s8v gf1 = ld_h(h0[par ^ 1], bm, 4 + hi4);
                const s8v hf0 = ld_h(h1[par],     bm, hi4);
                const s8v hf1 = ld_h(h1[par],     bm, 4 + hi4);

                f4v acc[4];
                #pragma unroll
                for (int g = 0; g < 4; ++g) {
                    f4v a = bias[g];
                    a = mfma_(wgh[g][0], gf0, a);
                    a = mfma_(wgl[g][0], gf0, a);
                    a = mfma_(wgh[g][1], gf1, a);
                    a = mfma_(wgl[g][1], gf1, a);
                    f4v b = {0.f, 0.f, 0.f, 0.f};
                    b = mfma_(whh[g][0], hf0, b);
                    b = mfma_(whl[g][0], hf0, b);
                    b = mfma_(whh[g][1], hf1, b);
                    b = mfma_(whl[g][1], hf1, b);
                    acc[g] = a + b;
                }
                float g4[4];
                #pragma unroll
                for (int g = 0; g < 4; ++g) {
                    float t0 = swz13(acc[g][0]);
                    float t1 = swz13(acc[g][1]);
                    float t2 = swz13(acc[g][2]);
                    float t3 = swz13(acc[g][3]);
                    float s01 = (rsel & 1) ? t1 : t0;
                    float s23 = (rsel & 1) ? t3 : t2;
                    g4[g] = (rsel & 2) ? s23 : s01;
                }
                float gi = sig_(g4[0]);
                float gf = sig_(g4[1]);
                float gg = tanh_(g4[2]);
                float go = sig_(g4[3]);
                c = gf * c + gi * gg;
                const float hv = go * tanh_(c);
                if (s < T) {
                    st_h16(h1[par ^ 1], bu, urow, f2bf(hv));
                } else {
                    part[wl][lane] = hv * fcwr;   // fc-head partial from fp32 h
                }
            }
            __syncthreads();
        }
    }

    // ---- fc head: out[b] = sum over rows of h1(T-1)[b]*fcw + fcb ----
    if (tid < 64) {
        float v = part[0][lane] + part[1][lane] + part[2][lane] + part[3][lane];
        v += __shfl_xor(v, 4);
        v += __shfl_xor(v, 8);
        v += __shfl_xor(v, 16);
        v += __shfl_xor(v, 32);
        if (lane < 4) out[b0 + lane] = v + fcb[0];
    }
}

extern "C" void kernel_launch(void* const* d_in, const int* in_sizes, int n_in,
                              void* d_out, int out_size, void* d_ws, size_t ws_size,
                              hipStream_t stream) {
    const float* x    = (const float*)d_in[0];
    const float* Wih0 = (const float*)d_in[1];
    const float* Whh0 = (const float*)d_in[2];
    const float* bih0 = (const float*)d_in[3];
    const float* bhh0 = (const float*)d_in[4];
    const float* Wih1 = (const float*)d_in[5];
    const float* Whh1 = (const float*)d_in[6];
    const float* bih1 = (const float*)d_in[7];
    const float* bhh1 = (const float*)d_in[8];
    const float* fcw  = (const float*)d_in[9];
    const float* fcb  = (const float*)d_in[10];
    float* out = (float*)d_out;

    const int B = out_size;                 // 1024
    const int T = in_sizes[0] / (B * F);    // 512

    dim3 grid(B / NB), block(NT);
    hipLaunchKernelGGL(lstm_nb4, grid, block, 0, stream,
                       x, Wih0, Whh0, bih0, bhh0,
                       Wih1, Whh1, bih1, bhh1, fcw, fcb,
                       out, T, B);
}

// Round 6
// 357.105 us; speedup vs baseline: 9.4606x; 1.2653x over previous
//
#include <hip/hip_runtime.h>
#include <math.h>

#define H  64
#define F  32
#define NB 4      // batch columns per block
#define NT 512    // 8 waves: 0-3 = layer0, 4-7 = layer1 (wave-specialized)
#define HS 80     // h row stride (shorts): 160B -> +8 banks/row, 2-way max
#define XS 40     // x row stride (shorts): 80B  -> +20 banks/row

typedef __attribute__((ext_vector_type(8))) short   s8v;   // 8 bf16 payload
typedef __attribute__((ext_vector_type(8))) __bf16  bf8v;  // MFMA operand type
typedef __attribute__((ext_vector_type(4))) float   f4v;   // MFMA accumulator

__device__ __forceinline__ unsigned short f2bf(float x) {
    unsigned u = __builtin_bit_cast(unsigned, x);
    u += 0x7FFFu + ((u >> 16) & 1u);          // RNE
    return (unsigned short)(u >> 16);
}
__device__ __forceinline__ float bf2f(unsigned short h) {
    unsigned u = ((unsigned)h) << 16;
    return __builtin_bit_cast(float, u);
}
// D = A*B + C ; A = activations (rows = batch-dup), B = weights (cols = gate rows)
__device__ __forceinline__ f4v mfma_(s8v a, s8v b, f4v c) {
    return __builtin_amdgcn_mfma_f32_16x16x32_bf16(
        __builtin_bit_cast(bf8v, a), __builtin_bit_cast(bf8v, b), c, 0, 0, 0);
}
__device__ __forceinline__ float sig_(float x) {
    return __builtin_amdgcn_rcpf(1.0f + __expf(-x));
}
__device__ __forceinline__ float tanh_(float x) {
    return 1.0f - 2.0f * __builtin_amdgcn_rcpf(1.0f + __expf(2.0f * x));
}

// Load an 8-wide B-fragment slice of a weight row, split hi/lo bf16.
__device__ __forceinline__ void load_frag(const float* __restrict__ Wrow, int koff,
                                          s8v& hi, s8v& lo) {
    #pragma unroll
    for (int i = 0; i < 8; ++i) {
        float v = Wrow[koff + i];
        unsigned short h = f2bf(v);
        hi[i] = (short)h;
        lo[i] = (short)f2bf(v - bf2f(h));
    }
}

__global__ __launch_bounds__(NT, 2)
void lstm_tr(const float* __restrict__ x,     // [B,T,F]
             const float* __restrict__ Wih0,  // [4H,F]
             const float* __restrict__ Whh0,  // [4H,H]
             const float* __restrict__ bih0,
             const float* __restrict__ bhh0,
             const float* __restrict__ Wih1,  // [4H,H]
             const float* __restrict__ Whh1,  // [4H,H]
             const float* __restrict__ bih1,
             const float* __restrict__ bhh1,
             const float* __restrict__ fcw,   // [1,H]
             const float* __restrict__ fcb,   // [1]
             float* __restrict__ out,         // [B]
             int T, int B)
{
    const int tid  = threadIdx.x;
    const int w    = tid >> 6;          // 0..7
    const int wl   = w & 3;             // wave within its layer group
    const bool isL0 = (w < 4);
    const int lane = tid & 63;
    const int j    = lane & 15;         // MFMA col: unit within wave's 16-unit group
    const int hi4  = lane >> 4;         // k-slice for fragments; batch for pointwise
    const int bm   = j >> 2;            // A-fragment batch row map  pi(m) = m>>2
    const int u    = 16 * wl + j;       // this lane's hidden unit
    const int b0   = blockIdx.x * NB;

    __shared__ alignas(16) unsigned short xh[2][NB][XS], xl[2][NB][XS];
    __shared__ alignas(16) unsigned short h0[2][NB][HS];
    __shared__ alignas(16) unsigned short h1[2][NB][HS];
    __shared__ float part[4][64];

    for (int i = tid; i < 2 * NB * HS; i += NT) {
        (&h0[0][0][0])[i] = 0;
        (&h1[0][0][0])[i] = 0;
    }

    if (isL0) {
        // ================= LAYER-0 WAVES =================
        s8v wxh[4], wxl[4];          // Wih0 hi/lo
        s8v whh[4][2], whl[4][2];    // Whh0 hi/lo
        float bias[4];
        #pragma unroll
        for (int g = 0; g < 4; ++g) {
            const int R = 64 * g + 16 * wl + j;
            load_frag(&Wih0[R * F], 8 * hi4, wxh[g], wxl[g]);
            #pragma unroll
            for (int kt = 0; kt < 2; ++kt)
                load_frag(&Whh0[R * H], 32 * kt + 8 * hi4, whh[g][kt], whl[g][kt]);
            bias[g] = bih0[R] + bhh0[R];
        }
        // stage x(0) and prefetch x(1): wave 0 only
        const int xb = tid >> 4, xk = 2 * (tid & 15);
        float2 xpre = {0.f, 0.f};
        if (tid < 64) {
            const float2 v0 = *(const float2*)&x[((size_t)(b0 + xb) * T + 0) * F + xk];
            ushort2 qh, ql;
            unsigned short a1 = f2bf(v0.x); qh.x = a1; ql.x = f2bf(v0.x - bf2f(a1));
            unsigned short a2 = f2bf(v0.y); qh.y = a2; ql.y = f2bf(v0.y - bf2f(a2));
            *(ushort2*)&xh[0][xb][xk] = qh;
            *(ushort2*)&xl[0][xb][xk] = ql;
            if (T > 1)
                xpre = *(const float2*)&x[((size_t)(b0 + xb) * T + 1) * F + xk];
        }
        __syncthreads();   // prolog barrier

        float c = 0.f;
        #pragma unroll 1
        for (int s = 0; s <= T; ++s) {
            const int par = s & 1;
            if (s < T) {
                // distance-2 x pipeline: write arrived x(s+1), issue x(s+2)
                if (tid < 64) {
                    if (s + 1 < T) {
                        ushort2 qh, ql;
                        unsigned short a1 = f2bf(xpre.x); qh.x = a1; ql.x = f2bf(xpre.x - bf2f(a1));
                        unsigned short a2 = f2bf(xpre.y); qh.y = a2; ql.y = f2bf(xpre.y - bf2f(a2));
                        *(ushort2*)&xh[par ^ 1][xb][xk] = qh;
                        *(ushort2*)&xl[par ^ 1][xb][xk] = ql;
                    }
                    if (s + 2 < T)
                        xpre = *(const float2*)&x[((size_t)(b0 + xb) * T + (s + 2)) * F + xk];
                }
                const s8v xfh = *(const s8v*)&xh[par][bm][8 * hi4];
                const s8v xfl = *(const s8v*)&xl[par][bm][8 * hi4];
                const s8v hf0 = *(const s8v*)&h0[par ^ 1][bm][8 * hi4];
                const s8v hf1 = *(const s8v*)&h0[par ^ 1][bm][8 * (4 + hi4)];

                f4v acc[4];
                #pragma unroll
                for (int g = 0; g < 4; ++g) {
                    f4v a = {bias[g], bias[g], bias[g], bias[g]};
                    a = mfma_(xfh, wxh[g], a);
                    a = mfma_(xfl, wxh[g], a);
                    a = mfma_(xfh, wxl[g], a);
                    f4v b = {0.f, 0.f, 0.f, 0.f};
                    b = mfma_(hf0, whh[g][0], b);
                    b = mfma_(hf0, whl[g][0], b);
                    b = mfma_(hf1, whh[g][1], b);
                    b = mfma_(hf1, whl[g][1], b);
                    acc[g] = a + b;
                }
                // all 4 regs identical (batch = hi4): pointwise straight off reg 0
                float gi = sig_(acc[0][0]);
                float gf = sig_(acc[1][0]);
                float gg = tanh_(acc[2][0]);
                float go = sig_(acc[3][0]);
                c = gf * c + gi * gg;
                h0[par][hi4][u] = f2bf(go * tanh_(c));
            }
            __syncthreads();
        }
    } else {
        // ================= LAYER-1 WAVES =================
        s8v wgh[4][2], wgl[4][2];    // Wih1 hi/lo
        s8v whh[4][2], whl[4][2];    // Whh1 hi/lo
        float bias[4];
        #pragma unroll
        for (int g = 0; g < 4; ++g) {
            const int R = 64 * g + 16 * wl + j;
            #pragma unroll
            for (int kt = 0; kt < 2; ++kt) {
                load_frag(&Wih1[R * H], 32 * kt + 8 * hi4, wgh[g][kt], wgl[g][kt]);
                load_frag(&Whh1[R * H], 32 * kt + 8 * hi4, whh[g][kt], whl[g][kt]);
            }
            bias[g] = bih1[R] + bhh1[R];
        }
        const float fcwr = fcw[u];
        __syncthreads();   // prolog barrier

        float c = 0.f;
        #pragma unroll 1
        for (int s = 0; s <= T; ++s) {
            const int par = s & 1;
            if (s >= 1) {
                // computes t = s-1: inputs h0(s-1) [buf par^1], h1(s-2) [buf par]
                const s8v gf0 = *(const s8v*)&h0[par ^ 1][bm][8 * hi4];
                const s8v gf1 = *(const s8v*)&h0[par ^ 1][bm][8 * (4 + hi4)];
                const s8v hf0 = *(const s8v*)&h1[par][bm][8 * hi4];
                const s8v hf1 = *(const s8v*)&h1[par][bm][8 * (4 + hi4)];

                f4v acc[4];
                #pragma unroll
                for (int g = 0; g < 4; ++g) {
                    f4v a = {bias[g], bias[g], bias[g], bias[g]};
                    a = mfma_(gf0, wgh[g][0], a);
                    a = mfma_(gf0, wgl[g][0], a);
                    a = mfma_(gf1, wgh[g][1], a);
                    a = mfma_(gf1, wgl[g][1], a);
                    f4v b = {0.f, 0.f, 0.f, 0.f};
                    b = mfma_(hf0, whh[g][0], b);
                    b = mfma_(hf0, whl[g][0], b);
                    b = mfma_(hf1, whh[g][1], b);
                    b = mfma_(hf1, whl[g][1], b);
                    acc[g] = a + b;
                }
                float gi = sig_(acc[0][0]);
                float gf = sig_(acc[1][0]);
                float gg = tanh_(acc[2][0]);
                float go = sig_(acc[3][0]);
                c = gf * c + gi * gg;
                const float hv = go * tanh_(c);
                if (s < T) {
                    h1[par ^ 1][hi4][u] = f2bf(hv);
                } else {
                    part[wl][lane] = hv * fcwr;   // fc-head partial from fp32 h
                }
            }
            __syncthreads();
        }
    }

    // ---- fc head: out[b] = sum_u h1(T-1)[b][u]*fcw[u] + fcb ----
    if (tid < 64) {
        float v = part[0][lane] + part[1][lane] + part[2][lane] + part[3][lane];
        v += __shfl_xor(v, 1);
        v += __shfl_xor(v, 2);
        v += __shfl_xor(v, 4);
        v += __shfl_xor(v, 8);
        if (j == 0) out[b0 + hi4] = v + fcb[0];
    }
}

extern "C" void kernel_launch(void* const* d_in, const int* in_sizes, int n_in,
                              void* d_out, int out_size, void* d_ws, size_t ws_size,
                              hipStream_t stream) {
    const float* x    = (const float*)d_in[0];
    const float* Wih0 = (const float*)d_in[1];
    const float* Whh0 = (const float*)d_in[2];
    const float* bih0 = (const float*)d_in[3];
    const float* bhh0 = (const float*)d_in[4];
    const float* Wih1 = (const float*)d_in[5];
    const float* Whh1 = (const float*)d_in[6];
    const float* bih1 = (const float*)d_in[7];
    const float* bhh1 = (const float*)d_in[8];
    const float* fcw  = (const float*)d_in[9];
    const float* fcb  = (const float*)d_in[10];
    float* out = (float*)d_out;

    const int B = out_size;                 // 1024
    const int T = in_sizes[0] / (B * F);    // 512

    dim3 grid(B / NB), block(NT);
    hipLaunchKernelGGL(lstm_tr, grid, block, 0, stream,
                       x, Wih0, Whh0, bih0, bhh0,
                       Wih1, Whh1, bih1, bhh1, fcw, fcb,
                       out, T, B);
}

// Round 7
// 258.016 us; speedup vs baseline: 13.0938x; 1.3840x over previous
//
#include <hip/hip_runtime.h>
#include <math.h>

#define H  64
#define F  32
#define NB 4      // batch columns per block
#define NT 512    // 8 waves: 0-3 = layer0, 4-7 = layer1 (wave-specialized)
#define HS 80     // h row stride (shorts): 160B -> +8 banks/row, 2-way max
#define XS 40     // x row stride (shorts): 80B  -> +20 banks/row

typedef __attribute__((ext_vector_type(8))) short   s8v;   // 8 bf16 payload
typedef __attribute__((ext_vector_type(8))) __bf16  bf8v;  // MFMA operand type
typedef __attribute__((ext_vector_type(4))) float   f4v;   // MFMA accumulator

__device__ __forceinline__ unsigned short f2bf(float x) {
    unsigned u = __builtin_bit_cast(unsigned, x);
    u += 0x7FFFu + ((u >> 16) & 1u);          // RNE
    return (unsigned short)(u >> 16);
}
__device__ __forceinline__ float bf2f(unsigned short h) {
    unsigned u = ((unsigned)h) << 16;
    return __builtin_bit_cast(float, u);
}
// D = A*B + C ; A = activations (rows = batch-dup), B = weights (cols = gate rows)
__device__ __forceinline__ f4v mfma_(s8v a, s8v b, f4v c) {
    return __builtin_amdgcn_mfma_f32_16x16x32_bf16(
        __builtin_bit_cast(bf8v, a), __builtin_bit_cast(bf8v, b), c, 0, 0, 0);
}
__device__ __forceinline__ float sig_(float x) {
    return __builtin_amdgcn_rcpf(1.0f + __expf(-x));
}
__device__ __forceinline__ float tanh_(float x) {
    return 1.0f - 2.0f * __builtin_amdgcn_rcpf(1.0f + __expf(2.0f * x));
}

// Load an 8-wide B-fragment slice of a weight row, bf16-hi only.
__device__ __forceinline__ s8v load_hi(const float* __restrict__ Wrow, int koff) {
    s8v hi;
    #pragma unroll
    for (int i = 0; i < 8; ++i) hi[i] = (short)f2bf(Wrow[koff + i]);
    return hi;
}

__global__ __launch_bounds__(NT, 2)
void lstm_hi(const float* __restrict__ x,     // [B,T,F]
             const float* __restrict__ Wih0,  // [4H,F]
             const float* __restrict__ Whh0,  // [4H,H]
             const float* __restrict__ bih0,
             const float* __restrict__ bhh0,
             const float* __restrict__ Wih1,  // [4H,H]
             const float* __restrict__ Whh1,  // [4H,H]
             const float* __restrict__ bih1,
             const float* __restrict__ bhh1,
             const float* __restrict__ fcw,   // [1,H]
             const float* __restrict__ fcb,   // [1]
             float* __restrict__ out,         // [B]
             int T, int B)
{
    const int tid  = threadIdx.x;
    const int w    = tid >> 6;          // 0..7
    const int wl   = w & 3;             // wave within its layer group
    const bool isL0 = (w < 4);
    const int lane = tid & 63;
    const int j    = lane & 15;         // MFMA col: unit within wave's 16-unit group
    const int hi4  = lane >> 4;         // k-slice for fragments; batch for pointwise
    const int bm   = j >> 2;            // A-fragment batch row map  pi(m) = m>>2
    const int u    = 16 * wl + j;       // this lane's hidden unit
    const int b0   = blockIdx.x * NB;

    __shared__ alignas(16) unsigned short xh[2][NB][XS], xl[2][NB][XS];
    __shared__ alignas(16) unsigned short h0[2][NB][HS];
    __shared__ alignas(16) unsigned short h1[2][NB][HS];
    __shared__ float part[4][64];

    for (int i = tid; i < 2 * NB * HS; i += NT) {
        (&h0[0][0][0])[i] = 0;
        (&h1[0][0][0])[i] = 0;
    }

    if (isL0) {
        // ================= LAYER-0 WAVES =================
        s8v wxh[4];          // Wih0 hi
        s8v whh[4][2];       // Whh0 hi
        float bias[4];
        #pragma unroll
        for (int g = 0; g < 4; ++g) {
            const int R = 64 * g + 16 * wl + j;
            wxh[g] = load_hi(&Wih0[R * F], 8 * hi4);
            #pragma unroll
            for (int kt = 0; kt < 2; ++kt)
                whh[g][kt] = load_hi(&Whh0[R * H], 32 * kt + 8 * hi4);
            bias[g] = bih0[R] + bhh0[R];
        }
        // stage x(0) and prefetch x(1): wave 0 only
        const int xb = tid >> 4, xk = 2 * (tid & 15);
        float2 xpre = {0.f, 0.f};
        if (tid < 64) {
            const float2 v0 = *(const float2*)&x[((size_t)(b0 + xb) * T + 0) * F + xk];
            ushort2 qh, ql;
            unsigned short a1 = f2bf(v0.x); qh.x = a1; ql.x = f2bf(v0.x - bf2f(a1));
            unsigned short a2 = f2bf(v0.y); qh.y = a2; ql.y = f2bf(v0.y - bf2f(a2));
            *(ushort2*)&xh[0][xb][xk] = qh;
            *(ushort2*)&xl[0][xb][xk] = ql;
            if (T > 1)
                xpre = *(const float2*)&x[((size_t)(b0 + xb) * T + 1) * F + xk];
        }
        __syncthreads();   // prolog barrier

        float c = 0.f;
        #pragma unroll 1
        for (int s = 0; s <= T; ++s) {
            const int par = s & 1;
            if (s < T) {
                // distance-2 x pipeline: write arrived x(s+1), issue x(s+2)
                if (tid < 64) {
                    if (s + 1 < T) {
                        ushort2 qh, ql;
                        unsigned short a1 = f2bf(xpre.x); qh.x = a1; ql.x = f2bf(xpre.x - bf2f(a1));
                        unsigned short a2 = f2bf(xpre.y); qh.y = a2; ql.y = f2bf(xpre.y - bf2f(a2));
                        *(ushort2*)&xh[par ^ 1][xb][xk] = qh;
                        *(ushort2*)&xl[par ^ 1][xb][xk] = ql;
                    }
                    if (s + 2 < T)
                        xpre = *(const float2*)&x[((size_t)(b0 + xb) * T + (s + 2)) * F + xk];
                }
                const s8v xfh = *(const s8v*)&xh[par][bm][8 * hi4];
                const s8v xfl = *(const s8v*)&xl[par][bm][8 * hi4];
                const s8v hf0 = *(const s8v*)&h0[par ^ 1][bm][8 * hi4];
                const s8v hf1 = *(const s8v*)&h0[par ^ 1][bm][8 * (4 + hi4)];

                f4v acc[4];
                #pragma unroll
                for (int g = 0; g < 4; ++g) {
                    f4v a = {bias[g], bias[g], bias[g], bias[g]};
                    a = mfma_(xfh, wxh[g], a);
                    a = mfma_(xfl, wxh[g], a);
                    f4v b = {0.f, 0.f, 0.f, 0.f};
                    b = mfma_(hf0, whh[g][0], b);
                    b = mfma_(hf1, whh[g][1], b);
                    acc[g] = a + b;
                }
                // all 4 regs identical (batch = hi4): pointwise straight off reg 0
                float gi = sig_(acc[0][0]);
                float gf = sig_(acc[1][0]);
                float gg = tanh_(acc[2][0]);
                float go = sig_(acc[3][0]);
                c = gf * c + gi * gg;
                h0[par][hi4][u] = f2bf(go * tanh_(c));
            }
            __syncthreads();
        }
    } else {
        // ================= LAYER-1 WAVES =================
        s8v wgh[4][2];       // Wih1 hi
        s8v whh[4][2];       // Whh1 hi
        float bias[4];
        #pragma unroll
        for (int g = 0; g < 4; ++g) {
            const int R = 64 * g + 16 * wl + j;
            #pragma unroll
            for (int kt = 0; kt < 2; ++kt) {
                wgh[g][kt] = load_hi(&Wih1[R * H], 32 * kt + 8 * hi4);
                whh[g][kt] = load_hi(&Whh1[R * H], 32 * kt + 8 * hi4);
            }
            bias[g] = bih1[R] + bhh1[R];
        }
        const float fcwr = fcw[u];
        __syncthreads();   // prolog barrier

        float c = 0.f;
        #pragma unroll 1
        for (int s = 0; s <= T; ++s) {
            const int par = s & 1;
            if (s >= 1) {
                // computes t = s-1: inputs h0(s-1) [buf par^1], h1(s-2) [buf par]
                const s8v gf0 = *(const s8v*)&h0[par ^ 1][bm][8 * hi4];
                const s8v gf1 = *(const s8v*)&h0[par ^ 1][bm][8 * (4 + hi4)];
                const s8v hf0 = *(const s8v*)&h1[par][bm][8 * hi4];
                const s8v hf1 = *(const s8v*)&h1[par][bm][8 * (4 + hi4)];

                f4v acc[4];
                #pragma unroll
                for (int g = 0; g < 4; ++g) {
                    f4v a = {bias[g], bias[g], bias[g], bias[g]};
                    a = mfma_(gf0, wgh[g][0], a);
                    a = mfma_(gf1, wgh[g][1], a);
                    f4v b = {0.f, 0.f, 0.f, 0.f};
                    b = mfma_(hf0, whh[g][0], b);
                    b = mfma_(hf1, whh[g][1], b);
                    acc[g] = a + b;
                }
                float gi = sig_(acc[0][0]);
                float gf = sig_(acc[1][0]);
                float gg = tanh_(acc[2][0]);
                float go = sig_(acc[3][0]);
                c = gf * c + gi * gg;
                const float hv = go * tanh_(c);
                if (s < T) {
                    h1[par ^ 1][hi4][u] = f2bf(hv);
                } else {
                    part[wl][lane] = hv * fcwr;   // fc-head partial from fp32 h
                }
            }
            __syncthreads();
        }
    }

    // ---- fc head: out[b] = sum_u h1(T-1)[b][u]*fcw[u] + fcb ----
    if (tid < 64) {
        float v = part[0][lane] + part[1][lane] + part[2][lane] + part[3][lane];
        v += __shfl_xor(v, 1);
        v += __shfl_xor(v, 2);
        v += __shfl_xor(v, 4);
        v += __shfl_xor(v, 8);
        if (j == 0) out[b0 + hi4] = v + fcb[0];
    }
}

extern "C" void kernel_launch(void* const* d_in, const int* in_sizes, int n_in,
                              void* d_out, int out_size, void* d_ws, size_t ws_size,
                              hipStream_t stream) {
    const float* x    = (const float*)d_in[0];
    const float* Wih0 = (const float*)d_in[1];
    const float* Whh0 = (const float*)d_in[2];
    const float* bih0 = (const float*)d_in[3];
    const float* bhh0 = (const float*)d_in[4];
    const float* Wih1 = (const float*)d_in[5];
    const float* Whh1 = (const float*)d_in[6];
    const float* bih1 = (const float*)d_in[7];
    const float* bhh1 = (const float*)d_in[8];
    const float* fcw  = (const float*)d_in[9];
    const float* fcb  = (const float*)d_in[10];
    float* out = (float*)d_out;

    const int B = out_size;                 // 1024
    const int T = in_sizes[0] / (B * F);    // 512

    dim3 grid(B / NB), block(NT);
    hipLaunchKernelGGL(lstm_hi, grid, block, 0, stream,
                       x, Wih0, Whh0, bih0, bhh0,
                       Wih1, Whh1, bih1, bhh1, fcw, fcb,
                       out, T, B);
}

// Round 8
// 234.243 us; speedup vs baseline: 14.4227x; 1.1015x over previous
//
#include <hip/hip_runtime.h>
#include <math.h>

#define H  64
#define F  32
#define NB 4      // batch columns per block
#define NT 512    // 8 waves: 0-3 = layer0, 4-7 = layer1 (wave-specialized)
#define HS 80     // h row stride (shorts): 160B -> 2-way banks max (free)
#define XS 40     // x row stride (shorts)

typedef __attribute__((ext_vector_type(8))) short   s8v;   // 8 bf16 payload
typedef __attribute__((ext_vector_type(8))) __bf16  bf8v;  // MFMA operand type
typedef __attribute__((ext_vector_type(4))) float   f4v;   // MFMA accumulator

__device__ __forceinline__ unsigned short f2bf(float x) {   // weight init only
    unsigned u = __builtin_bit_cast(unsigned, x);
    u += 0x7FFFu + ((u >> 16) & 1u);          // RNE
    return (unsigned short)(u >> 16);
}
// HW packed f32->bf16 RNE convert (1 instr): low16 = cvt(a), high16 = cvt(b)
__device__ __forceinline__ unsigned cvtpk(float a, float b) {
    unsigned r;
    asm volatile("v_cvt_pk_bf16_f32 %0, %1, %2" : "=v"(r) : "v"(a), "v"(b));
    return r;
}
// D = A*B + C ; A = activations (rows = batch-dup), B = weights (cols = gate rows)
__device__ __forceinline__ f4v mfma_(s8v a, s8v b, f4v c) {
    return __builtin_amdgcn_mfma_f32_16x16x32_bf16(
        __builtin_bit_cast(bf8v, a), __builtin_bit_cast(bf8v, b), c, 0, 0, 0);
}
__device__ __forceinline__ float sig_(float x) {
    return __builtin_amdgcn_rcpf(1.0f + __expf(-x));
}
__device__ __forceinline__ float tanh_(float x) {
    return 1.0f - 2.0f * __builtin_amdgcn_rcpf(1.0f + __expf(2.0f * x));
}

// Load an 8-wide B-fragment slice of a weight row, bf16-hi only.
__device__ __forceinline__ s8v load_hi(const float* __restrict__ Wrow, int koff) {
    s8v hi;
    #pragma unroll
    for (int i = 0; i < 8; ++i) hi[i] = (short)f2bf(Wrow[koff + i]);
    return hi;
}

__global__ __launch_bounds__(NT, 2)
void lstm_v8(const float* __restrict__ x,     // [B,T,F]
             const float* __restrict__ Wih0,  // [4H,F]
             const float* __restrict__ Whh0,  // [4H,H]
             const float* __restrict__ bih0,
             const float* __restrict__ bhh0,
             const float* __restrict__ Wih1,  // [4H,H]
             const float* __restrict__ Whh1,  // [4H,H]
             const float* __restrict__ bih1,
             const float* __restrict__ bhh1,
             const float* __restrict__ fcw,   // [1,H]
             const float* __restrict__ fcb,   // [1]
             float* __restrict__ out,         // [B]
             int T, int B)
{
    const int tid  = threadIdx.x;
    const int w    = tid >> 6;          // 0..7
    const int wl   = w & 3;             // wave within its layer group
    const bool isL0 = (w < 4);
    const int lane = tid & 63;
    const int j    = lane & 15;         // MFMA col: unit within wave's 16-unit group
    const int hi4  = lane >> 4;         // k-slice for fragments; batch for pointwise
    const int bm   = j >> 2;            // A-fragment batch row map  pi(m) = m>>2
    const int u    = 16 * wl + j;       // this lane's hidden unit
    const int b0   = blockIdx.x * NB;

    __shared__ alignas(16) unsigned short xh[2][NB][XS];
    __shared__ alignas(16) unsigned short h0[2][NB][HS];
    __shared__ alignas(16) unsigned short h1[2][NB][HS];
    __shared__ float part[4][64];

    for (int i = tid; i < 2 * NB * HS; i += NT) {
        (&h0[0][0][0])[i] = 0;
        (&h1[0][0][0])[i] = 0;
    }

    if (isL0) {
        // ================= LAYER-0 WAVES =================
        s8v wxh[4];          // Wih0 hi
        s8v whh[4][2];       // Whh0 hi
        float bias[4];
        #pragma unroll
        for (int g = 0; g < 4; ++g) {
            const int R = 64 * g + 16 * wl + j;
            wxh[g] = load_hi(&Wih0[R * F], 8 * hi4);
            #pragma unroll
            for (int kt = 0; kt < 2; ++kt)
                whh[g][kt] = load_hi(&Whh0[R * H], 32 * kt + 8 * hi4);
            bias[g] = bih0[R] + bhh0[R];
        }
        // x staging: 128 threads (waves 0-1), 1 float each; distance-2 pipeline
        const bool stager = (tid < 128);
        const int xb = tid >> 5, xk = tid & 31;
        const float* xsrc = x + ((size_t)(b0 + xb) * T) * F + xk;
        float xpre = 0.f;
        if (stager) {
            const float v0 = xsrc[0];
            xh[0][xb][xk] = (unsigned short)cvtpk(v0, v0);
            if (T > 1) xpre = xsrc[F];
        }
        __syncthreads();   // prolog barrier

        float c = 0.f;
        #pragma unroll 1
        for (int s = 0; s <= T; ++s) {
            const int par = s & 1;
            if (s < T) {
                // write arrived x(s+1), issue x(s+2)
                if (stager) {
                    if (s + 1 < T)
                        xh[par ^ 1][xb][xk] = (unsigned short)cvtpk(xpre, xpre);
                    if (s + 2 < T)
                        xpre = xsrc[(size_t)(s + 2) * F];
                }
                const s8v xfh = *(const s8v*)&xh[par][bm][8 * hi4];
                const s8v hf0 = *(const s8v*)&h0[par ^ 1][bm][8 * hi4];
                const s8v hf1 = *(const s8v*)&h0[par ^ 1][bm][8 * (4 + hi4)];

                f4v a[4], b[4];
                __builtin_amdgcn_s_setprio(1);
                #pragma unroll
                for (int g = 0; g < 4; ++g) {
                    f4v av = {bias[g], bias[g], bias[g], bias[g]};
                    a[g] = mfma_(xfh, wxh[g], av);
                    f4v bv = {0.f, 0.f, 0.f, 0.f};
                    bv = mfma_(hf0, whh[g][0], bv);
                    b[g] = mfma_(hf1, whh[g][1], bv);
                }
                __builtin_amdgcn_s_setprio(0);
                const float gi = sig_(a[0][0] + b[0][0]);
                const float gf = sig_(a[1][0] + b[1][0]);
                const float gg = tanh_(a[2][0] + b[2][0]);
                const float go = sig_(a[3][0] + b[3][0]);
                c = gf * c + gi * gg;
                const float hv = go * tanh_(c);
                h0[par][hi4][u] = (unsigned short)cvtpk(hv, hv);
            }
            __syncthreads();
        }
    } else {
        // ================= LAYER-1 WAVES =================
        s8v wgh[4][2];       // Wih1 hi
        s8v whh[4][2];       // Whh1 hi
        float bias[4];
        #pragma unroll
        for (int g = 0; g < 4; ++g) {
            const int R = 64 * g + 16 * wl + j;
            #pragma unroll
            for (int kt = 0; kt < 2; ++kt) {
                wgh[g][kt] = load_hi(&Wih1[R * H], 32 * kt + 8 * hi4);
                whh[g][kt] = load_hi(&Whh1[R * H], 32 * kt + 8 * hi4);
            }
            bias[g] = bih1[R] + bhh1[R];
        }
        const float fcwr = fcw[u];
        __syncthreads();   // prolog barrier

        float c = 0.f;
        #pragma unroll 1
        for (int s = 0; s <= T; ++s) {
            const int par = s & 1;
            if (s >= 1) {
                // computes t = s-1: inputs h0(s-1) [buf par^1], h1(s-2) [buf par]
                const s8v gf0 = *(const s8v*)&h0[par ^ 1][bm][8 * hi4];
                const s8v gf1 = *(const s8v*)&h0[par ^ 1][bm][8 * (4 + hi4)];
                const s8v hf0 = *(const s8v*)&h1[par][bm][8 * hi4];
                const s8v hf1 = *(const s8v*)&h1[par][bm][8 * (4 + hi4)];

                f4v a[4], b[4];
                __builtin_amdgcn_s_setprio(1);
                #pragma unroll
                for (int g = 0; g < 4; ++g) {
                    f4v av = {bias[g], bias[g], bias[g], bias[g]};
                    av = mfma_(gf0, wgh[g][0], av);
                    a[g] = mfma_(gf1, wgh[g][1], av);
                    f4v bv = {0.f, 0.f, 0.f, 0.f};
                    bv = mfma_(hf0, whh[g][0], bv);
                    b[g] = mfma_(hf1, whh[g][1], bv);
                }
                __builtin_amdgcn_s_setprio(0);
                const float gi = sig_(a[0][0] + b[0][0]);
                const float gf = sig_(a[1][0] + b[1][0]);
                const float gg = tanh_(a[2][0] + b[2][0]);
                const float go = sig_(a[3][0] + b[3][0]);
                c = gf * c + gi * gg;
                const float hv = go * tanh_(c);
                if (s < T) {
                    h1[par ^ 1][hi4][u] = (unsigned short)cvtpk(hv, hv);
                } else {
                    part[wl][lane] = hv * fcwr;   // fc-head partial from fp32 h
                }
            }
            __syncthreads();
        }
    }

    // ---- fc head: out[b] = sum_u h1(T-1)[b][u]*fcw[u] + fcb ----
    if (tid < 64) {
        float v = part[0][lane] + part[1][lane] + part[2][lane] + part[3][lane];
        v += __shfl_xor(v, 1);
        v += __shfl_xor(v, 2);
        v += __shfl_xor(v, 4);
        v += __shfl_xor(v, 8);
        if (j == 0) out[b0 + hi4] = v + fcb[0];
    }
}

extern "C" void kernel_launch(void* const* d_in, const int* in_sizes, int n_in,
                              void* d_out, int out_size, void* d_ws, size_t ws_size,
                              hipStream_t stream) {
    const float* x    = (const float*)d_in[0];
    const float* Wih0 = (const float*)d_in[1];
    const float* Whh0 = (const float*)d_in[2];
    const float* bih0 = (const float*)d_in[3];
    const float* bhh0 = (const float*)d_in[4];
    const float* Wih1 = (const float*)d_in[5];
    const float* Whh1 = (const float*)d_in[6];
    const float* bih1 = (const float*)d_in[7];
    const float* bhh1 = (const float*)d_in[8];
    const float* fcw  = (const float*)d_in[9];
    const float* fcb  = (const float*)d_in[10];
    float* out = (float*)d_out;

    const int B = out_size;                 // 1024
    const int T = in_sizes[0] / (B * F);    // 512

    dim3 grid(B / NB), block(NT);
    hipLaunchKernelGGL(lstm_v8, grid, block, 0, stream,
                       x, Wih0, Whh0, bih0, bhh0,
                       Wih1, Whh1, bih1, bhh1, fcw, fcb,
                       out, T, B);
}

// Round 9
// 210.359 us; speedup vs baseline: 16.0603x; 1.1135x over previous
//
#include <hip/hip_runtime.h>
#include <math.h>

#define H  64
#define F  32
#define NB 4      // batch columns per block
#define NT 512    // 8 waves: 0-3 = layer0, 4-7 = layer1 (wave-specialized)
#define HS 80     // h row stride (shorts): 160B -> 2-way banks max (free)

typedef __attribute__((ext_vector_type(8))) short   s8v;   // 8 bf16 payload
typedef __attribute__((ext_vector_type(8))) __bf16  bf8v;  // MFMA operand type
typedef __attribute__((ext_vector_type(4))) float   f4v;   // MFMA accumulator

__device__ __forceinline__ unsigned short f2bf(float x) {   // weight init only
    unsigned u = __builtin_bit_cast(unsigned, x);
    u += 0x7FFFu + ((u >> 16) & 1u);          // RNE
    return (unsigned short)(u >> 16);
}
// HW packed f32->bf16 RNE convert (1 instr): low16 = cvt(a), high16 = cvt(b)
__device__ __forceinline__ unsigned cvtpk(float a, float b) {
    unsigned r;
    asm("v_cvt_pk_bf16_f32 %0, %1, %2" : "=v"(r) : "v"(a), "v"(b));
    return r;
}
// D = A*B + C ; A = activations (rows = batch-dup), B = weights (cols = gate rows)
__device__ __forceinline__ f4v mfma_(s8v a, s8v b, f4v c) {
    return __builtin_amdgcn_mfma_f32_16x16x32_bf16(
        __builtin_bit_cast(bf8v, a), __builtin_bit_cast(bf8v, b), c, 0, 0, 0);
}
__device__ __forceinline__ float sig_(float x) {
    return __builtin_amdgcn_rcpf(1.0f + __expf(-x));
}
__device__ __forceinline__ float tanh_(float x) {
    return 1.0f - 2.0f * __builtin_amdgcn_rcpf(1.0f + __expf(2.0f * x));
}
// LDS-flush + raw barrier: does NOT drain vmcnt (x loads stay in flight)
__device__ __forceinline__ void bar_lds() {
    asm volatile("s_waitcnt lgkmcnt(0)" ::: "memory");
    __builtin_amdgcn_s_barrier();
}

// Load an 8-wide B-fragment slice of a weight row, bf16-hi only.
__device__ __forceinline__ s8v load_hi(const float* __restrict__ Wrow, int koff) {
    s8v hi;
    #pragma unroll
    for (int i = 0; i < 8; ++i) hi[i] = (short)f2bf(Wrow[koff + i]);
    return hi;
}

__global__ __launch_bounds__(NT, 2)
void lstm_v9(const float* __restrict__ x,     // [B,T,F]
             const float* __restrict__ Wih0,  // [4H,F]
             const float* __restrict__ Whh0,  // [4H,H]
             const float* __restrict__ bih0,
             const float* __restrict__ bhh0,
             const float* __restrict__ Wih1,  // [4H,H]
             const float* __restrict__ Whh1,  // [4H,H]
             const float* __restrict__ bih1,
             const float* __restrict__ bhh1,
             const float* __restrict__ fcw,   // [1,H]
             const float* __restrict__ fcb,   // [1]
             float* __restrict__ out,         // [B]
             int T, int B)
{
    const int tid  = threadIdx.x;
    const int w    = tid >> 6;          // 0..7
    const int wl   = w & 3;             // wave within its layer group
    const bool isL0 = (w < 4);
    const int lane = tid & 63;
    const int j    = lane & 15;         // MFMA col: unit within wave's 16-unit group
    const int hi4  = lane >> 4;         // k-slice for fragments; batch for pointwise
    const int bm   = j >> 2;            // A-fragment batch row map  pi(m) = m>>2
    const int u    = 16 * wl + j;       // this lane's hidden unit
    const int b0   = blockIdx.x * NB;

    __shared__ alignas(16) unsigned short h0[2][NB][HS];
    __shared__ alignas(16) unsigned short h1[2][NB][HS];
    __shared__ float part[4][64];

    for (int i = tid; i < 2 * NB * HS; i += NT) {
        (&h0[0][0][0])[i] = 0;
        (&h1[0][0][0])[i] = 0;
    }

    if (isL0) {
        // ================= LAYER-0 WAVES =================
        s8v wxh[4];          // Wih0 hi
        s8v whh[4][2];       // Whh0 hi
        float bias[4];
        #pragma unroll
        for (int g = 0; g < 4; ++g) {
            const int R = 64 * g + 16 * wl + j;
            wxh[g] = load_hi(&Wih0[R * F], 8 * hi4);
            #pragma unroll
            for (int kt = 0; kt < 2; ++kt)
                whh[g][kt] = load_hi(&Whh0[R * H], 32 * kt + 8 * hi4);
            bias[g] = bih0[R] + bhh0[R];
        }
        // x direct-load: this lane's 8-float slice of its batch row
        const float* xrow = x + ((size_t)(b0 + bm) * T) * F + 8 * hi4;
        float4 xA0 = *(const float4*)(xrow);          // t=0
        float4 xA1 = *(const float4*)(xrow + 4);
        float4 xB0 = *(const float4*)(xrow + F);      // t=1
        float4 xB1 = *(const float4*)(xrow + F + 4);

        __syncthreads();   // prolog barrier (h zeros visible)

        float c = 0.f;
        auto stepL0 = [&](int s, int par, float4& xr0, float4& xr1) {
            // x(s) fragment from in-flight registers (bit-identical bf16 RNE)
            s8v xf;
            unsigned* xfu = (unsigned*)&xf;
            xfu[0] = cvtpk(xr0.x, xr0.y);
            xfu[1] = cvtpk(xr0.z, xr0.w);
            xfu[2] = cvtpk(xr1.x, xr1.y);
            xfu[3] = cvtpk(xr1.z, xr1.w);
            // issue x(s+2) load into the same regs (consumed 2 steps later)
            const size_t tld = (size_t)((s + 2 < T) ? (s + 2) : (T - 1)) * F;
            xr0 = *(const float4*)(xrow + tld);
            xr1 = *(const float4*)(xrow + tld + 4);

            const s8v hf0 = *(const s8v*)&h0[par ^ 1][bm][8 * hi4];
            const s8v hf1 = *(const s8v*)&h0[par ^ 1][bm][8 * (4 + hi4)];

            f4v a[4], b[4];
            __builtin_amdgcn_s_setprio(1);
            #pragma unroll
            for (int g = 0; g < 4; ++g) {
                f4v av = {bias[g], bias[g], bias[g], bias[g]};
                a[g] = mfma_(xf, wxh[g], av);
                f4v bv = {0.f, 0.f, 0.f, 0.f};
                bv = mfma_(hf0, whh[g][0], bv);
                b[g] = mfma_(hf1, whh[g][1], bv);
            }
            __builtin_amdgcn_s_setprio(0);
            const float gi = sig_(a[0][0] + b[0][0]);
            const float gf = sig_(a[1][0] + b[1][0]);
            const float gg = tanh_(a[2][0] + b[2][0]);
            const float go = sig_(a[3][0] + b[3][0]);
            c = gf * c + gi * gg;
            const float hv = go * tanh_(c);
            h0[par][hi4][u] = (unsigned short)cvtpk(hv, hv);
            bar_lds();
        };

        #pragma unroll 1
        for (int s = 0; s < T; s += 2) {       // T even
            stepL0(s,     0, xA0, xA1);
            stepL0(s + 1, 1, xB0, xB1);
        }
        bar_lds();   // tail step s=T: L0 idle (barrier count match)
    } else {
        // ================= LAYER-1 WAVES =================
        s8v wgh[4][2];       // Wih1 hi
        s8v whh[4][2];       // Whh1 hi
        float bias[4];
        #pragma unroll
        for (int g = 0; g < 4; ++g) {
            const int R = 64 * g + 16 * wl + j;
            #pragma unroll
            for (int kt = 0; kt < 2; ++kt) {
                wgh[g][kt] = load_hi(&Wih1[R * H], 32 * kt + 8 * hi4);
                whh[g][kt] = load_hi(&Whh1[R * H], 32 * kt + 8 * hi4);
            }
            bias[g] = bih1[R] + bhh1[R];
        }
        const float fcwr = fcw[u];
        __syncthreads();   // prolog barrier

        float c = 0.f;
        auto stepL1 = [&](int s, int par) {
            if (s >= 1) {
                // computes t = s-1: inputs h0(s-1) [buf par^1], h1(s-2) [buf par]
                const s8v gf0 = *(const s8v*)&h0[par ^ 1][bm][8 * hi4];
                const s8v gf1 = *(const s8v*)&h0[par ^ 1][bm][8 * (4 + hi4)];
                const s8v hf0 = *(const s8v*)&h1[par][bm][8 * hi4];
                const s8v hf1 = *(const s8v*)&h1[par][bm][8 * (4 + hi4)];

                f4v a[4], b[4];
                __builtin_amdgcn_s_setprio(1);
                #pragma unroll
                for (int g = 0; g < 4; ++g) {
                    f4v av = {bias[g], bias[g], bias[g], bias[g]};
                    av = mfma_(gf0, wgh[g][0], av);
                    a[g] = mfma_(gf1, wgh[g][1], av);
                    f4v bv = {0.f, 0.f, 0.f, 0.f};
                    bv = mfma_(hf0, whh[g][0], bv);
                    b[g] = mfma_(hf1, whh[g][1], bv);
                }
                __builtin_amdgcn_s_setprio(0);
                const float gi = sig_(a[0][0] + b[0][0]);
                const float gf = sig_(a[1][0] + b[1][0]);
                const float gg = tanh_(a[2][0] + b[2][0]);
                const float go = sig_(a[3][0] + b[3][0]);
                c = gf * c + gi * gg;
                const float hv = go * tanh_(c);
                if (s < T) {
                    h1[par ^ 1][hi4][u] = (unsigned short)cvtpk(hv, hv);
                } else {
                    part[wl][lane] = hv * fcwr;   // fc-head partial from fp32 h
                }
            }
            bar_lds();
        };

        #pragma unroll 1
        for (int s = 0; s < T; s += 2) {       // T even
            stepL1(s,     0);
            stepL1(s + 1, 1);
        }
        stepL1(T, 0);   // tail: computes t=T-1 -> part
    }

    __syncthreads();   // part[] visible (full barrier, drains everything)

    // ---- fc head: out[b] = sum_u h1(T-1)[b][u]*fcw[u] + fcb ----
    if (tid < 64) {
        float v = part[0][lane] + part[1][lane] + part[2][lane] + part[3][lane];
        v += __shfl_xor(v, 1);
        v += __shfl_xor(v, 2);
        v += __shfl_xor(v, 4);
        v += __shfl_xor(v, 8);
        if (j == 0) out[b0 + hi4] = v + fcb[0];
    }
}

extern "C" void kernel_launch(void* const* d_in, const int* in_sizes, int n_in,
                              void* d_out, int out_size, void* d_ws, size_t ws_size,
                              hipStream_t stream) {
    const float* x    = (const float*)d_in[0];
    const float* Wih0 = (const float*)d_in[1];
    const float* Whh0 = (const float*)d_in[2];
    const float* bih0 = (const float*)d_in[3];
    const float* bhh0 = (const float*)d_in[4];
    const float* Wih1 = (const float*)d_in[5];
    const float* Whh1 = (const float*)d_in[6];
    const float* bih1 = (const float*)d_in[7];
    const float* bhh1 = (const float*)d_in[8];
    const float* fcw  = (const float*)d_in[9];
    const float* fcb  = (const float*)d_in[10];
    float* out = (float*)d_out;

    const int B = out_size;                 // 1024
    const int T = in_sizes[0] / (B * F);    // 512

    dim3 grid(B / NB), block(NT);
    hipLaunchKernelGGL(lstm_v9, grid, block, 0, stream,
                       x, Wih0, Whh0, bih0, bhh0,
                       Wih1, Whh1, bih1, bhh1, fcw, fcb,
                       out, T, B);
}